// Round 13
// baseline (143.062 us; speedup 1.0000x reference)
//
#include <hip/hip_runtime.h>
#include <hip/hip_bf16.h>
#include <math.h>

#define NN 50000
#define HIDD 96
#define NH 8
#define HD 12
#define FFND 384
#define NE 800000
#define NB 98            // buckets of 512 dst nodes
#define BSTRIDE 12288    // fixed edge capacity per bucket (mean 8192, +45 sigma)

#define INV_SCALE 0.28867513459481287f
#define LOG2E 1.4426950408889634f

typedef short short8 __attribute__((ext_vector_type(8)));
typedef float f32x4 __attribute__((ext_vector_type(4)));
typedef float f32x2 __attribute__((ext_vector_type(2)));

__device__ __forceinline__ float bf2f(unsigned short u) {
    union { unsigned int i; float f; } c;
    c.i = ((unsigned int)u) << 16;
    return c.f;
}

// ---------------- P1: gcursor-init ∥ wconv ∥ ln1 (one launch) ----------------
__global__ __launch_bounds__(256) void prep(
    int* __restrict__ gcursor,
    const float* __restrict__ Wq, const float* __restrict__ Wk,
    const float* __restrict__ Wv, const float* __restrict__ Wo,
    const float* __restrict__ W1, const float* __restrict__ W2,
    __hip_bfloat16* __restrict__ wbuf,
    const float* __restrict__ x, const float* __restrict__ g1,
    const float* __restrict__ b1, __hip_bfloat16* __restrict__ ybf) {
    int b = blockIdx.x;
    int t = threadIdx.x;
    if (b == 0) {
        if (t < 128) gcursor[t] = t * BSTRIDE;
        return;
    }
    if (b < 433) {
        int idx = b - 1;
        const float* W; __hip_bfloat16* D; int K, N; int i;
        if (idx < 144)      { W = W1; D = wbuf + 36864; K = 96;  N = 384; i = idx * 256 + t; }
        else if (idx < 288) { W = W2; D = wbuf + 73728; K = 384; N = 96;  i = (idx - 144) * 256 + t; }
        else {
            int slab = (idx - 288) / 36;
            W = (slab == 0) ? Wq : (slab == 1) ? Wk : (slab == 2) ? Wv : Wo;
            D = wbuf + slab * 9216; K = 96; N = 96;
            i = ((idx - 288) % 36) * 256 + t;
        }
        if (i < K * N) {
            int n = i / K, k = i % K;
            D[i] = __float2bfloat16(W[k * N + n]);
        }
    } else {
        int row = (b - 433) * 4 + (t >> 6);
        int lane = t & 63;
        if (row >= NN) return;
        const float* xr = x + (size_t)row * HIDD;
        float v0 = xr[lane];
        float v1 = (lane < 32) ? xr[64 + lane] : 0.0f;
        float s = v0 + v1, q = v0 * v0 + v1 * v1;
#pragma unroll
        for (int o = 32; o > 0; o >>= 1) {
            s += __shfl_xor(s, o);
            q += __shfl_xor(q, o);
        }
        float mean = s * (1.0f / 96.0f);
        float var = q * (1.0f / 96.0f) - mean * mean;
        float rs = rsqrtf(var + 1e-5f);
        __hip_bfloat16* yr = ybf + (size_t)row * HIDD;
        yr[lane] = __float2bfloat16((v0 - mean) * rs * g1[lane] + b1[lane]);
        if (lane < 32)
            yr[64 + lane] = __float2bfloat16((v1 - mean) * rs * g1[64 + lane] + b1[64 + lane]);
    }
}

// ---------------- MFMA GEMM body (LDS-staged B) ----------------
// SMODE: 0 = fp32 flat, 1 = bf16 flat, 2 = fp8 kv-interleaved (+koff)
template<int K, int EPI, int SMODE>
__device__ __forceinline__ void gemm_body(
    const __hip_bfloat16* __restrict__ A, const __hip_bfloat16* __restrict__ BT,
    const float* __restrict__ bias, const __hip_bfloat16* __restrict__ R,
    void* __restrict__ Cptr, int ldc, int col0, int koff, int xb) {
    constexpr int BK = (K > 192) ? 192 : K;
    __shared__ __hip_bfloat16 Bs[96][BK + 8];
    int t = threadIdx.x;
    int lane = t & 63, wave = t >> 6;
    int row0 = xb * 128 + wave * 32;
    int lr = lane & 15, kg = lane >> 4;
    bool val0 = (row0 + 16 <= NN);
    bool val1 = (row0 + 32 <= NN);
    int ra0 = val0 ? row0 : 0;
    int ra1 = val1 ? (row0 + 16) : 0;
    const __hip_bfloat16* A0 = A + (size_t)(ra0 + lr) * K + kg * 8;
    const __hip_bfloat16* A1 = A + (size_t)(ra1 + lr) * K + kg * 8;
    f32x4 acc[2][6];
#pragma unroll
    for (int f = 0; f < 2; f++)
#pragma unroll
        for (int ct = 0; ct < 6; ct++) acc[f][ct] = (f32x4){0.f, 0.f, 0.f, 0.f};

    for (int k0 = 0; k0 < K; k0 += BK) {
        for (int i = t * 8; i < 96 * BK; i += 256 * 8) {
            int r = i / BK, c = i % BK;
            *(short8*)&Bs[r][c] = *(const short8*)&BT[(size_t)r * K + k0 + c];
        }
        __syncthreads();
#pragma unroll
        for (int kc = 0; kc < BK; kc += 32) {
            short8 a0 = *(const short8*)(A0 + k0 + kc);
            short8 a1 = *(const short8*)(A1 + k0 + kc);
#pragma unroll
            for (int ct = 0; ct < 6; ct++) {
                short8 bf_ = *(const short8*)&Bs[ct * 16 + lr][kc + kg * 8];
                acc[0][ct] = __builtin_amdgcn_mfma_f32_16x16x32_bf16(a0, bf_, acc[0][ct], 0, 0, 0);
                acc[1][ct] = __builtin_amdgcn_mfma_f32_16x16x32_bf16(a1, bf_, acc[1][ct], 0, 0, 0);
            }
        }
        __syncthreads();
    }

#pragma unroll
    for (int f = 0; f < 2; f++) {
        if (f == 0 ? !val0 : !val1) continue;
        int crow = row0 + f * 16 + kg * 4;
#pragma unroll
        for (int ct = 0; ct < 6; ct++) {
            int col = col0 + ct * 16 + lr;
            float bb = bias[col];
#pragma unroll
            for (int r = 0; r < 4; r++) {
                float o = acc[f][ct][r] + bb;
                if (EPI == 1)
                    o = 0.5f * o * (1.0f + erff(o * 0.70710678118654752f));
                if (EPI == 2)
                    o += __bfloat162float(R[(size_t)(crow + r) * 96 + col]);
                if (SMODE == 0)
                    ((float*)Cptr)[(size_t)(crow + r) * ldc + col] = o;
                else if (SMODE == 1)
                    ((__hip_bfloat16*)Cptr)[(size_t)(crow + r) * ldc + col] = __float2bfloat16(o);
                else {
                    unsigned int enc = (unsigned int)__builtin_amdgcn_cvt_pk_fp8_f32(o, o, 0, false);
                    ((unsigned char*)Cptr)[(size_t)(crow + r) * 192 + ((col - col0) / 12) * 24 + koff + ((col - col0) % 12)]
                        = (unsigned char)(enc & 0xffu);
                }
            }
        }
    }
}

// ---------------- P2: bucket_scatter ∥ qkv MFMA (one launch) ----------------
__global__ __launch_bounds__(256) void scatter_qkv(
    const int* __restrict__ ei, int* __restrict__ gcursor,
    unsigned int* __restrict__ ebuf,
    const __hip_bfloat16* __restrict__ A, const __hip_bfloat16* __restrict__ wbuf,
    const float* __restrict__ bq, const float* __restrict__ bk,
    const float* __restrict__ bv,
    __hip_bfloat16* __restrict__ qbf, unsigned char* __restrict__ kv) {
    int b = blockIdx.x;
    if (b < 391) {
        __shared__ int lcount[128];
        __shared__ int lbase[128];
        int t = threadIdx.x;
        int e0 = b * 2048;
        if (t < 128) lcount[t] = 0;
        __syncthreads();
        int rank[8], dsts[8], srcv[8];
#pragma unroll
        for (int i = 0; i < 8; i++) {
            int e = e0 + t + i * 256;
            if (e < NE) {
                srcv[i] = ei[e];
                int d = ei[NE + e];
                dsts[i] = d;
                rank[i] = atomicAdd(&lcount[d >> 9], 1);
            } else dsts[i] = -1;
        }
        __syncthreads();
        if (t < 128) lbase[t] = lcount[t] ? atomicAdd(&gcursor[t], lcount[t]) : 0;
        __syncthreads();
#pragma unroll
        for (int i = 0; i < 8; i++) {
            if (dsts[i] >= 0) {
                int bk_ = dsts[i] >> 9;
                ebuf[lbase[bk_] + rank[i]] =
                    ((unsigned int)dsts[i] << 16) | (unsigned int)srcv[i];
            }
        }
    } else {
        int idx = b - 391;
        int y = idx / 391, xb = idx % 391;
        if (y == 0)
            gemm_body<96, 0, 1>(A, wbuf, bq, nullptr, qbf, 96, 0, 0, xb);
        else if (y == 1)
            gemm_body<96, 0, 2>(A, wbuf + 9216, bk, nullptr, kv, 0, 0, 0, xb);
        else
            gemm_body<96, 0, 2>(A, wbuf + 18432, bv, nullptr, kv, 0, 0, 12, xb);
    }
}

// ---------------- bucket build (1024 thr) ----------------
__global__ __launch_bounds__(1024) void bucket_build(
    const unsigned int* __restrict__ ebuf, const int* __restrict__ gcursor,
    uint2* __restrict__ rowrange, unsigned short* __restrict__ srcs) {
    __shared__ int cnt[512];
    int b = blockIdx.x;
    int t = threadIdx.x;
    int n0 = b * 512;
    int beg = b * BSTRIDE;
    int end = gcursor[b];
    if (t < 512) cnt[t] = 0;
    __syncthreads();
    for (int e = beg + t; e < end; e += 1024)
        atomicAdd(&cnt[(ebuf[e] >> 16) - n0], 1);
    __syncthreads();
    int my = (t < 512) ? cnt[t] : 0;
    for (int off = 1; off < 512; off <<= 1) {
        int v = (t >= off && t < 512) ? cnt[t - off] : 0;
        __syncthreads();
        if (t < 512) cnt[t] += v;
        __syncthreads();
    }
    int excl = (t > 0 && t < 512) ? cnt[t - 1] : 0;
    int base = beg + excl;
    if (t < 512 && n0 + t < NN)
        rowrange[n0 + t] = make_uint2((unsigned)base, (unsigned)(base + my));
    __syncthreads();
    if (t < 512) cnt[t] = base;
    __syncthreads();
    for (int e = beg + t; e < end; e += 1024) {
        unsigned int u = ebuf[e];
        int pos = atomicAdd(&cnt[(u >> 16) - n0], 1);
        srcs[pos] = (unsigned short)(u & 0xffffu);
    }
}

// ---------------- proj + LN2 fused (x2 out in bf16) ----------------
__global__ __launch_bounds__(256) void proj_ln(
    const __hip_bfloat16* __restrict__ A, const __hip_bfloat16* __restrict__ BT,
    const float* __restrict__ bias, const float* __restrict__ R,
    const float* __restrict__ g2, const float* __restrict__ b2v,
    __hip_bfloat16* __restrict__ x2, __hip_bfloat16* __restrict__ ybf) {
    constexpr int K = 96;
    __shared__ __hip_bfloat16 Bs[96][K + 8];
    int t = threadIdx.x;
    int lane = t & 63, wave = t >> 6;
    int row0 = blockIdx.x * 128 + wave * 32;
    int lr = lane & 15, kg = lane >> 4;
    bool val0 = (row0 + 16 <= NN);
    bool val1 = (row0 + 32 <= NN);
    int ra0 = val0 ? row0 : 0;
    int ra1 = val1 ? (row0 + 16) : 0;
    const __hip_bfloat16* A0 = A + (size_t)(ra0 + lr) * K + kg * 8;
    const __hip_bfloat16* A1 = A + (size_t)(ra1 + lr) * K + kg * 8;
    f32x4 acc[2][6];
#pragma unroll
    for (int f = 0; f < 2; f++)
#pragma unroll
        for (int ct = 0; ct < 6; ct++) acc[f][ct] = (f32x4){0.f, 0.f, 0.f, 0.f};

    for (int i = t * 8; i < 96 * K; i += 256 * 8) {
        int r = i / K, c = i % K;
        *(short8*)&Bs[r][c] = *(const short8*)&BT[(size_t)r * K + c];
    }
    __syncthreads();
#pragma unroll
    for (int kc = 0; kc < K; kc += 32) {
        short8 a0 = *(const short8*)(A0 + kc);
        short8 a1 = *(const short8*)(A1 + kc);
#pragma unroll
        for (int ct = 0; ct < 6; ct++) {
            short8 bf_ = *(const short8*)&Bs[ct * 16 + lr][kc + kg * 8];
            acc[0][ct] = __builtin_amdgcn_mfma_f32_16x16x32_bf16(a0, bf_, acc[0][ct], 0, 0, 0);
            acc[1][ct] = __builtin_amdgcn_mfma_f32_16x16x32_bf16(a1, bf_, acc[1][ct], 0, 0, 0);
        }
    }

    float bo_[6], gv[6], bv_[6];
#pragma unroll
    for (int ct = 0; ct < 6; ct++) {
        int col = ct * 16 + lr;
        bo_[ct] = bias[col];
        gv[ct]  = g2[col];
        bv_[ct] = b2v[col];
    }
#pragma unroll
    for (int f = 0; f < 2; f++) {
        if (f == 0 ? !val0 : !val1) continue;
        int crow = row0 + f * 16 + kg * 4;
#pragma unroll
        for (int r = 0; r < 4; r++) {
            int row = crow + r;
            float o[6], s1 = 0.f, s2 = 0.f;
#pragma unroll
            for (int ct = 0; ct < 6; ct++) {
                int col = ct * 16 + lr;
                float val = acc[f][ct][r] + bo_[ct] + R[(size_t)row * 96 + col];
                o[ct] = val; s1 += val; s2 += val * val;
            }
#pragma unroll
            for (int m = 1; m < 16; m <<= 1) {
                s1 += __shfl_xor(s1, m);
                s2 += __shfl_xor(s2, m);
            }
            float mu = s1 * (1.0f / 96.0f);
            float var = s2 * (1.0f / 96.0f) - mu * mu;
            float rs = rsqrtf(var + 1e-5f);
#pragma unroll
            for (int ct = 0; ct < 6; ct++) {
                int col = ct * 16 + lr;
                x2[(size_t)row * 96 + col] = __float2bfloat16(o[ct]);
                ybf[(size_t)row * 96 + col] =
                    __float2bfloat16((o[ct] - mu) * rs * gv[ct] + bv_[ct]);
            }
        }
    }
}

// ---------------- Fused FFN: out = x2 + gelu(ybf@W1+b1)@W2 + b2 ----------------
// Block = 64 rows, 4 waves x 16 rows. h lives in LDS only (never global).
__global__ __launch_bounds__(256) void ffn_fused(
    const __hip_bfloat16* __restrict__ ybf, const __hip_bfloat16* __restrict__ W1T,
    const __hip_bfloat16* __restrict__ W2T, const float* __restrict__ b1,
    const float* __restrict__ b2v, const __hip_bfloat16* __restrict__ x2,
    float* __restrict__ out) {
    __shared__ __hip_bfloat16 hlds[64][392];   // padded: stride 98 dwords
    __shared__ __hip_bfloat16 Bs[96][104];
    int t = threadIdx.x, lane = t & 63, wave = t >> 6;
    int row0 = blockIdx.x * 64;
    int lr = lane & 15, kg = lane >> 4;
    int rw = row0 + wave * 16;
    bool valid = (rw + 16 <= NN);
    int ra = valid ? rw : 0;

    // preload GEMM1 A-frags (ybf rows, K=96)
    short8 af[3];
#pragma unroll
    for (int kc = 0; kc < 3; kc++)
        af[kc] = *(const short8*)&ybf[(size_t)(ra + lr) * 96 + kc * 32 + kg * 8];

    // ---- GEMM1: h = gelu(ybf @ W1 + b1), 4 slabs of 96 cols ----
    for (int s = 0; s < 4; s++) {
        for (int i = t * 8; i < 96 * 96; i += 256 * 8) {
            int r = i / 96, c = i % 96;
            *(short8*)&Bs[r][c] = *(const short8*)&W1T[(size_t)(s * 96 + r) * 96 + c];
        }
        __syncthreads();
        f32x4 acc[6];
#pragma unroll
        for (int ct = 0; ct < 6; ct++) acc[ct] = (f32x4){0.f, 0.f, 0.f, 0.f};
#pragma unroll
        for (int kc = 0; kc < 3; kc++) {
#pragma unroll
            for (int ct = 0; ct < 6; ct++) {
                short8 bf_ = *(const short8*)&Bs[ct * 16 + lr][kc * 32 + kg * 8];
                acc[ct] = __builtin_amdgcn_mfma_f32_16x16x32_bf16(af[kc], bf_, acc[ct], 0, 0, 0);
            }
        }
#pragma unroll
        for (int ct = 0; ct < 6; ct++) {
            int col = s * 96 + ct * 16 + lr;
            float bb = b1[col];
#pragma unroll
            for (int r = 0; r < 4; r++) {
                float o = acc[ct][r] + bb;
                o = 0.5f * o * (1.0f + erff(o * 0.70710678118654752f));
                hlds[wave * 16 + kg * 4 + r][col] = __float2bfloat16(o);
            }
        }
        __syncthreads();
    }

    // ---- GEMM2: out = h @ W2 + b2 + x2, K=384 in 4 chunks ----
    f32x4 acc2[6];
#pragma unroll
    for (int ct = 0; ct < 6; ct++) acc2[ct] = (f32x4){0.f, 0.f, 0.f, 0.f};
    for (int c = 0; c < 4; c++) {
        for (int i = t * 8; i < 96 * 96; i += 256 * 8) {
            int r = i / 96, cc = i % 96;
            *(short8*)&Bs[r][cc] = *(const short8*)&W2T[(size_t)r * 384 + c * 96 + cc];
        }
        __syncthreads();
#pragma unroll
        for (int kc = 0; kc < 3; kc++) {
            short8 a = *(const short8*)&hlds[wave * 16 + lr][c * 96 + kc * 32 + kg * 8];
#pragma unroll
            for (int ct = 0; ct < 6; ct++) {
                short8 bf_ = *(const short8*)&Bs[ct * 16 + lr][kc * 32 + kg * 8];
                acc2[ct] = __builtin_amdgcn_mfma_f32_16x16x32_bf16(a, bf_, acc2[ct], 0, 0, 0);
            }
        }
        __syncthreads();
    }

    if (valid) {
        int crow = rw + kg * 4;
#pragma unroll
        for (int ct = 0; ct < 6; ct++) {
            int col = ct * 16 + lr;
            float bb = b2v[col];
#pragma unroll
            for (int r = 0; r < 4; r++) {
                float o = acc2[ct][r] + bb
                        + __bfloat162float(x2[(size_t)(crow + r) * 96 + col]);
                out[(size_t)(crow + r) * 96 + col] = o;
            }
        }
    }
}

// ---------------- Sparse attention gather (fp8 kv, software-pipelined) ----------------
__global__ __launch_bounds__(256) void attn_gather(
    const __hip_bfloat16* __restrict__ qbf, const unsigned char* __restrict__ kv,
    const uint2* __restrict__ rowrange, const unsigned short* __restrict__ srcs,
    __hip_bfloat16* __restrict__ abf) {
    int wave = (blockIdx.x * blockDim.x + threadIdx.x) >> 6;
    int lane = threadIdx.x & 63;
    if (wave >= NN) return;
    int dst = wave;
    int h = lane & 7;
    int eslot = lane >> 3;
    float qf[12];
    {
        const uint2* qp = (const uint2*)(qbf + (size_t)dst * HIDD + h * HD);
        uint2 u0 = qp[0], u1 = qp[1], u2 = qp[2];
        unsigned int w[6] = {u0.x, u0.y, u1.x, u1.y, u2.x, u2.y};
#pragma unroll
        for (int i = 0; i < 6; i++) {
            qf[2 * i]     = bf2f((unsigned short)(w[i] & 0xffffu));
            qf[2 * i + 1] = bf2f((unsigned short)(w[i] >> 16));
        }
    }
    uint2 rr = rowrange[dst];
    int beg = (int)rr.x, end = (int)rr.y;
    float acc[12];
#pragma unroll
    for (int i = 0; i < 12; i++) acc[i] = 0.0f;
    float zz = 0.0f;

    int e = beg + eslot;
    bool has = e < end;
    uint2 cA, cB, cC;
    if (has) {
        int src = (int)srcs[e];
        const uint2* kp = (const uint2*)(kv + (size_t)src * 192 + h * 24);
        cA = kp[0]; cB = kp[1]; cC = kp[2];
    }
    while (has) {
        int en = e + 8;
        bool hasn = en < end;
        uint2 nA, nB, nC;
        if (hasn) {
            int srcn = (int)srcs[en];
            const uint2* kp = (const uint2*)(kv + (size_t)srcn * 192 + h * 24);
            nA = kp[0]; nB = kp[1]; nC = kp[2];
        }
        f32x2 p;
        float dot = 0.0f;
        p = __builtin_amdgcn_cvt_pk_f32_fp8(cA.x, false); dot += p[0] * qf[0]  + p[1] * qf[1];
        p = __builtin_amdgcn_cvt_pk_f32_fp8(cA.x, true);  dot += p[0] * qf[2]  + p[1] * qf[3];
        p = __builtin_amdgcn_cvt_pk_f32_fp8(cA.y, false); dot += p[0] * qf[4]  + p[1] * qf[5];
        p = __builtin_amdgcn_cvt_pk_f32_fp8(cA.y, true);  dot += p[0] * qf[6]  + p[1] * qf[7];
        p = __builtin_amdgcn_cvt_pk_f32_fp8(cB.x, false); dot += p[0] * qf[8]  + p[1] * qf[9];
        p = __builtin_amdgcn_cvt_pk_f32_fp8(cB.x, true);  dot += p[0] * qf[10] + p[1] * qf[11];
        float s = fminf(fmaxf(dot * INV_SCALE, -5.0f), 5.0f);
        float sc = exp2f(s * LOG2E);
        p = __builtin_amdgcn_cvt_pk_f32_fp8(cB.y, false); acc[0]  += p[0] * sc; acc[1]  += p[1] * sc;
        p = __builtin_amdgcn_cvt_pk_f32_fp8(cB.y, true);  acc[2]  += p[0] * sc; acc[3]  += p[1] * sc;
        p = __builtin_amdgcn_cvt_pk_f32_fp8(cC.x, false); acc[4]  += p[0] * sc; acc[5]  += p[1] * sc;
        p = __builtin_amdgcn_cvt_pk_f32_fp8(cC.x, true);  acc[6]  += p[0] * sc; acc[7]  += p[1] * sc;
        p = __builtin_amdgcn_cvt_pk_f32_fp8(cC.y, false); acc[8]  += p[0] * sc; acc[9]  += p[1] * sc;
        p = __builtin_amdgcn_cvt_pk_f32_fp8(cC.y, true);  acc[10] += p[0] * sc; acc[11] += p[1] * sc;
        zz += sc;
        cA = nA; cB = nB; cC = nC;
        e = en; has = hasn;
    }
#pragma unroll
    for (int m = 8; m < 64; m <<= 1) {
#pragma unroll
        for (int i = 0; i < 12; i++) acc[i] += __shfl_xor(acc[i], m);
        zz += __shfl_xor(zz, m);
    }
    if (eslot == 0) {
        float inv = 1.0f / (zz + 1e-6f);
        __hip_bfloat16* ar = abf + (size_t)dst * HIDD + h * HD;
#pragma unroll
        for (int i = 0; i < 12; i++) ar[i] = __float2bfloat16(acc[i] * inv);
    }
}

extern "C" void kernel_launch(void* const* d_in, const int* in_sizes, int n_in,
                              void* d_out, int out_size, void* d_ws, size_t ws_size,
                              hipStream_t stream) {
    const float* x     = (const float*)d_in[0];
    const int*   ei    = (const int*)d_in[1];
    const float* ln1_g = (const float*)d_in[2];
    const float* ln1_b = (const float*)d_in[3];
    const float* Wq    = (const float*)d_in[4];
    const float* bq    = (const float*)d_in[5];
    const float* Wk    = (const float*)d_in[6];
    const float* bk    = (const float*)d_in[7];
    const float* Wv    = (const float*)d_in[8];
    const float* bv    = (const float*)d_in[9];
    const float* Wo    = (const float*)d_in[10];
    const float* bo    = (const float*)d_in[11];
    const float* ln2_g = (const float*)d_in[12];
    const float* ln2_b = (const float*)d_in[13];
    const float* W1    = (const float*)d_in[14];
    const float* b1    = (const float*)d_in[15];
    const float* W2    = (const float*)d_in[16];
    const float* b2    = (const float*)d_in[17];
    float* out = (float*)d_out;

    // Workspace layout (float units, NF = NN*96 = 4.8M floats):
    //   qbf  bf16 [0, 0.5NF)
    //   kv   fp8  [0.5NF, NF)       (NN*192 bytes)
    //   abf  bf16 [1.5NF, 2NF)
    //   x2   bf16 [2NF, 2.5NF)
    //   ybf  bf16 [2.5NF, 3NF)
    //   CSR at 3NF: rowrange[NN] uint2, srcs[NB*BSTRIDE] u16, gcursor[128],
    //               ebuf[NB*BSTRIDE] u32
    //   wbuf bf16 at 3.5NF (110592 bf16)
    float* ws = (float*)d_ws;
    const size_t NF = (size_t)NN * HIDD;
    __hip_bfloat16* qbf = (__hip_bfloat16*)ws;
    unsigned char*  kv  = (unsigned char*)(ws + NF / 2);
    __hip_bfloat16* abf = (__hip_bfloat16*)(ws + NF / 2 + NF);
    __hip_bfloat16* x2  = (__hip_bfloat16*)(ws + 2 * NF);
    __hip_bfloat16* ybf = (__hip_bfloat16*)(ws + 2 * NF + NF / 2);
    int* ibase = (int*)(ws + 3 * NF);
    uint2* rowrange = (uint2*)ibase;                              // NN uint2
    unsigned short* srcs = (unsigned short*)(ibase + 2 * NN);     // NB*BSTRIDE u16
    int* gcursor = ibase + 2 * NN + (NB * BSTRIDE + 1) / 2;       // 128
    unsigned int* ebuf = (unsigned int*)(gcursor + 128);          // NB*BSTRIDE u32
    __hip_bfloat16* wbuf = (__hip_bfloat16*)(ws + 3 * NF + NF / 2);
    __hip_bfloat16* WoT = wbuf + 27648;
    __hip_bfloat16* W1T = wbuf + 36864;
    __hip_bfloat16* W2T = wbuf + 73728;

    const int MT = (NN + 127) / 128;             // 391
    const int FT = (NN + 63) / 64;               // 782

    // 1. P1: gcursor-init ∥ wconv ∥ LN1
    prep<<<433 + 12500, 256, 0, stream>>>(gcursor, Wq, Wk, Wv, Wo, W1, W2, wbuf,
                                          x, ln1_g, ln1_b, ybf);
    // 2. P2: bucket_scatter (fixed-stride) ∥ qkv MFMA
    scatter_qkv<<<391 + 3 * MT, 256, 0, stream>>>(ei, gcursor, ebuf,
                                                  ybf, wbuf, bq, bk, bv, qbf, kv);
    // 3. per-bucket CSR finalize
    bucket_build<<<NB, 1024, 0, stream>>>(ebuf, gcursor, rowrange, srcs);
    // 4. sparse attention
    attn_gather<<<(NN + 3) / 4, 256, 0, stream>>>(qbf, kv, rowrange, srcs, abf);
    // 5. output projection + residual + LN2 (x2 in bf16)
    proj_ln<<<MT, 256, 0, stream>>>(abf, WoT, bo, x, ln2_g, ln2_b, x2, ybf);
    // 6. fused FFN (h in LDS only)
    ffn_fused<<<FT, 256, 0, stream>>>(ybf, W1T, W2T, b1, b2, x2, out);
}

// Round 14
// 139.337 us; speedup vs baseline: 1.0267x; 1.0267x over previous
//
#include <hip/hip_runtime.h>
#include <hip/hip_bf16.h>
#include <math.h>

#define NN 50000
#define HIDD 96
#define NH 8
#define HD 12
#define FFND 384
#define NE 800000
#define NB 98            // buckets of 512 dst nodes
#define BSTRIDE 12288    // fixed edge capacity per bucket (mean 8192, +45 sigma)

#define INV_SCALE 0.28867513459481287f
#define LOG2E 1.4426950408889634f

typedef short short8 __attribute__((ext_vector_type(8)));
typedef float f32x4 __attribute__((ext_vector_type(4)));
typedef float f32x2 __attribute__((ext_vector_type(2)));

__device__ __forceinline__ float bf2f(unsigned short u) {
    union { unsigned int i; float f; } c;
    c.i = ((unsigned int)u) << 16;
    return c.f;
}

// ---------------- P1: gcursor-init ∥ wconv ∥ ln1 (one launch) ----------------
__global__ __launch_bounds__(256) void prep(
    int* __restrict__ gcursor,
    const float* __restrict__ Wq, const float* __restrict__ Wk,
    const float* __restrict__ Wv, const float* __restrict__ Wo,
    const float* __restrict__ W1, const float* __restrict__ W2,
    __hip_bfloat16* __restrict__ wbuf,
    const float* __restrict__ x, const float* __restrict__ g1,
    const float* __restrict__ b1, __hip_bfloat16* __restrict__ ybf) {
    int b = blockIdx.x;
    int t = threadIdx.x;
    if (b == 0) {
        if (t < 128) gcursor[t] = t * BSTRIDE;
        return;
    }
    if (b < 433) {
        int idx = b - 1;
        const float* W; __hip_bfloat16* D; int K, N; int i;
        if (idx < 144)      { W = W1; D = wbuf + 36864; K = 96;  N = 384; i = idx * 256 + t; }
        else if (idx < 288) { W = W2; D = wbuf + 73728; K = 384; N = 96;  i = (idx - 144) * 256 + t; }
        else {
            int slab = (idx - 288) / 36;
            W = (slab == 0) ? Wq : (slab == 1) ? Wk : (slab == 2) ? Wv : Wo;
            D = wbuf + slab * 9216; K = 96; N = 96;
            i = ((idx - 288) % 36) * 256 + t;
        }
        if (i < K * N) {
            int n = i / K, k = i % K;
            D[i] = __float2bfloat16(W[k * N + n]);
        }
    } else {
        int row = (b - 433) * 4 + (t >> 6);
        int lane = t & 63;
        if (row >= NN) return;
        const float* xr = x + (size_t)row * HIDD;
        float v0 = xr[lane];
        float v1 = (lane < 32) ? xr[64 + lane] : 0.0f;
        float s = v0 + v1, q = v0 * v0 + v1 * v1;
#pragma unroll
        for (int o = 32; o > 0; o >>= 1) {
            s += __shfl_xor(s, o);
            q += __shfl_xor(q, o);
        }
        float mean = s * (1.0f / 96.0f);
        float var = q * (1.0f / 96.0f) - mean * mean;
        float rs = rsqrtf(var + 1e-5f);
        __hip_bfloat16* yr = ybf + (size_t)row * HIDD;
        yr[lane] = __float2bfloat16((v0 - mean) * rs * g1[lane] + b1[lane]);
        if (lane < 32)
            yr[64 + lane] = __float2bfloat16((v1 - mean) * rs * g1[64 + lane] + b1[64 + lane]);
    }
}

// ---------------- MFMA GEMM body (LDS-staged B) ----------------
// SMODE: 0 = fp32 flat, 1 = bf16 flat, 2 = fp8 kv-interleaved (+koff)
template<int K, int EPI, int SMODE>
__device__ __forceinline__ void gemm_body(
    const __hip_bfloat16* __restrict__ A, const __hip_bfloat16* __restrict__ BT,
    const float* __restrict__ bias, const __hip_bfloat16* __restrict__ R,
    void* __restrict__ Cptr, int ldc, int col0, int koff, int xb) {
    constexpr int BK = (K > 192) ? 192 : K;
    __shared__ __hip_bfloat16 Bs[96][BK + 8];
    int t = threadIdx.x;
    int lane = t & 63, wave = t >> 6;
    int row0 = xb * 128 + wave * 32;
    int lr = lane & 15, kg = lane >> 4;
    bool val0 = (row0 + 16 <= NN);
    bool val1 = (row0 + 32 <= NN);
    int ra0 = val0 ? row0 : 0;
    int ra1 = val1 ? (row0 + 16) : 0;
    const __hip_bfloat16* A0 = A + (size_t)(ra0 + lr) * K + kg * 8;
    const __hip_bfloat16* A1 = A + (size_t)(ra1 + lr) * K + kg * 8;
    f32x4 acc[2][6];
#pragma unroll
    for (int f = 0; f < 2; f++)
#pragma unroll
        for (int ct = 0; ct < 6; ct++) acc[f][ct] = (f32x4){0.f, 0.f, 0.f, 0.f};

    for (int k0 = 0; k0 < K; k0 += BK) {
        for (int i = t * 8; i < 96 * BK; i += 256 * 8) {
            int r = i / BK, c = i % BK;
            *(short8*)&Bs[r][c] = *(const short8*)&BT[(size_t)r * K + k0 + c];
        }
        __syncthreads();
#pragma unroll
        for (int kc = 0; kc < BK; kc += 32) {
            short8 a0 = *(const short8*)(A0 + k0 + kc);
            short8 a1 = *(const short8*)(A1 + k0 + kc);
#pragma unroll
            for (int ct = 0; ct < 6; ct++) {
                short8 bf_ = *(const short8*)&Bs[ct * 16 + lr][kc + kg * 8];
                acc[0][ct] = __builtin_amdgcn_mfma_f32_16x16x32_bf16(a0, bf_, acc[0][ct], 0, 0, 0);
                acc[1][ct] = __builtin_amdgcn_mfma_f32_16x16x32_bf16(a1, bf_, acc[1][ct], 0, 0, 0);
            }
        }
        __syncthreads();
    }

#pragma unroll
    for (int f = 0; f < 2; f++) {
        if (f == 0 ? !val0 : !val1) continue;
        int crow = row0 + f * 16 + kg * 4;
#pragma unroll
        for (int ct = 0; ct < 6; ct++) {
            int col = col0 + ct * 16 + lr;
            float bb = bias[col];
#pragma unroll
            for (int r = 0; r < 4; r++) {
                float o = acc[f][ct][r] + bb;
                if (EPI == 1)
                    o = 0.5f * o * (1.0f + erff(o * 0.70710678118654752f));
                if (EPI == 2)
                    o += __bfloat162float(R[(size_t)(crow + r) * 96 + col]);
                if (SMODE == 0)
                    ((float*)Cptr)[(size_t)(crow + r) * ldc + col] = o;
                else if (SMODE == 1)
                    ((__hip_bfloat16*)Cptr)[(size_t)(crow + r) * ldc + col] = __float2bfloat16(o);
                else {
                    unsigned int enc = (unsigned int)__builtin_amdgcn_cvt_pk_fp8_f32(o, o, 0, false);
                    ((unsigned char*)Cptr)[(size_t)(crow + r) * 192 + ((col - col0) / 12) * 24 + koff + ((col - col0) % 12)]
                        = (unsigned char)(enc & 0xffu);
                }
            }
        }
    }
}

// ---------------- P2: bucket_scatter ∥ qkv MFMA (one launch) ----------------
__global__ __launch_bounds__(256) void scatter_qkv(
    const int* __restrict__ ei, int* __restrict__ gcursor,
    unsigned int* __restrict__ ebuf,
    const __hip_bfloat16* __restrict__ A, const __hip_bfloat16* __restrict__ wbuf,
    const float* __restrict__ bq, const float* __restrict__ bk,
    const float* __restrict__ bv,
    __hip_bfloat16* __restrict__ qbf, unsigned char* __restrict__ kv) {
    int b = blockIdx.x;
    if (b < 391) {
        __shared__ int lcount[128];
        __shared__ int lbase[128];
        int t = threadIdx.x;
        int e0 = b * 2048;
        if (t < 128) lcount[t] = 0;
        __syncthreads();
        int rank[8], dsts[8], srcv[8];
#pragma unroll
        for (int i = 0; i < 8; i++) {
            int e = e0 + t + i * 256;
            if (e < NE) {
                srcv[i] = ei[e];
                int d = ei[NE + e];
                dsts[i] = d;
                rank[i] = atomicAdd(&lcount[d >> 9], 1);
            } else dsts[i] = -1;
        }
        __syncthreads();
        if (t < 128) lbase[t] = lcount[t] ? atomicAdd(&gcursor[t], lcount[t]) : 0;
        __syncthreads();
#pragma unroll
        for (int i = 0; i < 8; i++) {
            if (dsts[i] >= 0) {
                int bk_ = dsts[i] >> 9;
                ebuf[lbase[bk_] + rank[i]] =
                    ((unsigned int)dsts[i] << 16) | (unsigned int)srcv[i];
            }
        }
    } else {
        int idx = b - 391;
        int y = idx / 391, xb = idx % 391;
        if (y == 0)
            gemm_body<96, 0, 1>(A, wbuf, bq, nullptr, qbf, 96, 0, 0, xb);
        else if (y == 1)
            gemm_body<96, 0, 2>(A, wbuf + 9216, bk, nullptr, kv, 0, 0, 0, xb);
        else
            gemm_body<96, 0, 2>(A, wbuf + 18432, bv, nullptr, kv, 0, 0, 12, xb);
    }
}

// ---------------- bucket build (1024 thr) ----------------
__global__ __launch_bounds__(1024) void bucket_build(
    const unsigned int* __restrict__ ebuf, const int* __restrict__ gcursor,
    uint2* __restrict__ rowrange, unsigned short* __restrict__ srcs) {
    __shared__ int cnt[512];
    int b = blockIdx.x;
    int t = threadIdx.x;
    int n0 = b * 512;
    int beg = b * BSTRIDE;
    int end = gcursor[b];
    if (t < 512) cnt[t] = 0;
    __syncthreads();
    for (int e = beg + t; e < end; e += 1024)
        atomicAdd(&cnt[(ebuf[e] >> 16) - n0], 1);
    __syncthreads();
    int my = (t < 512) ? cnt[t] : 0;
    for (int off = 1; off < 512; off <<= 1) {
        int v = (t >= off && t < 512) ? cnt[t - off] : 0;
        __syncthreads();
        if (t < 512) cnt[t] += v;
        __syncthreads();
    }
    int excl = (t > 0 && t < 512) ? cnt[t - 1] : 0;
    int base = beg + excl;
    if (t < 512 && n0 + t < NN)
        rowrange[n0 + t] = make_uint2((unsigned)base, (unsigned)(base + my));
    __syncthreads();
    if (t < 512) cnt[t] = base;
    __syncthreads();
    for (int e = beg + t; e < end; e += 1024) {
        unsigned int u = ebuf[e];
        int pos = atomicAdd(&cnt[(u >> 16) - n0], 1);
        srcs[pos] = (unsigned short)(u & 0xffffu);
    }
}

// ---------------- proj + LN2 fused (x2 out in bf16) ----------------
__global__ __launch_bounds__(256) void proj_ln(
    const __hip_bfloat16* __restrict__ A, const __hip_bfloat16* __restrict__ BT,
    const float* __restrict__ bias, const float* __restrict__ R,
    const float* __restrict__ g2, const float* __restrict__ b2v,
    __hip_bfloat16* __restrict__ x2, __hip_bfloat16* __restrict__ ybf) {
    constexpr int K = 96;
    __shared__ __hip_bfloat16 Bs[96][K + 8];
    int t = threadIdx.x;
    int lane = t & 63, wave = t >> 6;
    int row0 = blockIdx.x * 128 + wave * 32;
    int lr = lane & 15, kg = lane >> 4;
    bool val0 = (row0 + 16 <= NN);
    bool val1 = (row0 + 32 <= NN);
    int ra0 = val0 ? row0 : 0;
    int ra1 = val1 ? (row0 + 16) : 0;
    const __hip_bfloat16* A0 = A + (size_t)(ra0 + lr) * K + kg * 8;
    const __hip_bfloat16* A1 = A + (size_t)(ra1 + lr) * K + kg * 8;
    f32x4 acc[2][6];
#pragma unroll
    for (int f = 0; f < 2; f++)
#pragma unroll
        for (int ct = 0; ct < 6; ct++) acc[f][ct] = (f32x4){0.f, 0.f, 0.f, 0.f};

    for (int i = t * 8; i < 96 * K; i += 256 * 8) {
        int r = i / K, c = i % K;
        *(short8*)&Bs[r][c] = *(const short8*)&BT[(size_t)r * K + c];
    }
    __syncthreads();
#pragma unroll
    for (int kc = 0; kc < K; kc += 32) {
        short8 a0 = *(const short8*)(A0 + kc);
        short8 a1 = *(const short8*)(A1 + kc);
#pragma unroll
        for (int ct = 0; ct < 6; ct++) {
            short8 bf_ = *(const short8*)&Bs[ct * 16 + lr][kc + kg * 8];
            acc[0][ct] = __builtin_amdgcn_mfma_f32_16x16x32_bf16(a0, bf_, acc[0][ct], 0, 0, 0);
            acc[1][ct] = __builtin_amdgcn_mfma_f32_16x16x32_bf16(a1, bf_, acc[1][ct], 0, 0, 0);
        }
    }

    float bo_[6], gv[6], bv_[6];
#pragma unroll
    for (int ct = 0; ct < 6; ct++) {
        int col = ct * 16 + lr;
        bo_[ct] = bias[col];
        gv[ct]  = g2[col];
        bv_[ct] = b2v[col];
    }
#pragma unroll
    for (int f = 0; f < 2; f++) {
        if (f == 0 ? !val0 : !val1) continue;
        int crow = row0 + f * 16 + kg * 4;
#pragma unroll
        for (int r = 0; r < 4; r++) {
            int row = crow + r;
            float o[6], s1 = 0.f, s2 = 0.f;
#pragma unroll
            for (int ct = 0; ct < 6; ct++) {
                int col = ct * 16 + lr;
                float val = acc[f][ct][r] + bo_[ct] + R[(size_t)row * 96 + col];
                o[ct] = val; s1 += val; s2 += val * val;
            }
#pragma unroll
            for (int m = 1; m < 16; m <<= 1) {
                s1 += __shfl_xor(s1, m);
                s2 += __shfl_xor(s2, m);
            }
            float mu = s1 * (1.0f / 96.0f);
            float var = s2 * (1.0f / 96.0f) - mu * mu;
            float rs = rsqrtf(var + 1e-5f);
#pragma unroll
            for (int ct = 0; ct < 6; ct++) {
                int col = ct * 16 + lr;
                x2[(size_t)row * 96 + col] = __float2bfloat16(o[ct]);
                ybf[(size_t)row * 96 + col] =
                    __float2bfloat16((o[ct] - mu) * rs * gv[ct] + bv_[ct]);
            }
        }
    }
}

// ---------------- FFN1 persistent-weight: h = gelu(ybf@W1+b1) ----------------
// grid (98, 4): block stages its 96-col W1 slab once, grid-strides row-tiles,
// zero barriers in the tile loop.
__global__ __launch_bounds__(256) void ffn1_p(
    const __hip_bfloat16* __restrict__ ybf, const __hip_bfloat16* __restrict__ W1T,
    const float* __restrict__ b1, __hip_bfloat16* __restrict__ hbf) {
    __shared__ __hip_bfloat16 Bs[96][104];
    int t = threadIdx.x, lane = t & 63, wave = t >> 6;
    int s = blockIdx.y;
    int lr = lane & 15, kg = lane >> 4;
    const __hip_bfloat16* slab = W1T + (size_t)s * 96 * 96;
    for (int i = t * 8; i < 96 * 96; i += 256 * 8) {
        int r = i / 96, c = i % 96;
        *(short8*)&Bs[r][c] = *(const short8*)&slab[r * 96 + c];
    }
    __syncthreads();
    float bb[6];
#pragma unroll
    for (int ct = 0; ct < 6; ct++) bb[ct] = b1[s * 96 + ct * 16 + lr];

    for (int tile = blockIdx.x; tile < 391; tile += 98) {
        int row0 = tile * 128 + wave * 32;
        bool val0 = (row0 + 16 <= NN);
        bool val1 = (row0 + 32 <= NN);
        int ra0 = val0 ? row0 : 0;
        int ra1 = val1 ? (row0 + 16) : 0;
        short8 a0[3], a1[3];
#pragma unroll
        for (int kc = 0; kc < 3; kc++) {
            a0[kc] = *(const short8*)&ybf[(size_t)(ra0 + lr) * 96 + kc * 32 + kg * 8];
            a1[kc] = *(const short8*)&ybf[(size_t)(ra1 + lr) * 96 + kc * 32 + kg * 8];
        }
        f32x4 acc[2][6];
#pragma unroll
        for (int f = 0; f < 2; f++)
#pragma unroll
            for (int ct = 0; ct < 6; ct++) acc[f][ct] = (f32x4){0.f, 0.f, 0.f, 0.f};
#pragma unroll
        for (int kc = 0; kc < 3; kc++) {
#pragma unroll
            for (int ct = 0; ct < 6; ct++) {
                short8 bf_ = *(const short8*)&Bs[ct * 16 + lr][kc * 32 + kg * 8];
                acc[0][ct] = __builtin_amdgcn_mfma_f32_16x16x32_bf16(a0[kc], bf_, acc[0][ct], 0, 0, 0);
                acc[1][ct] = __builtin_amdgcn_mfma_f32_16x16x32_bf16(a1[kc], bf_, acc[1][ct], 0, 0, 0);
            }
        }
#pragma unroll
        for (int f = 0; f < 2; f++) {
            if (f == 0 ? !val0 : !val1) continue;
            int crow = row0 + f * 16 + kg * 4;
#pragma unroll
            for (int ct = 0; ct < 6; ct++) {
                int col = s * 96 + ct * 16 + lr;
#pragma unroll
                for (int r = 0; r < 4; r++) {
                    float o = acc[f][ct][r] + bb[ct];
                    o = 0.5f * o * (1.0f + erff(o * 0.70710678118654752f));
                    hbf[(size_t)(crow + r) * FFND + col] = __float2bfloat16(o);
                }
            }
        }
    }
}

// ---------------- FFN2 persistent-weight: out = x2 + h@W2 + b2 ----------------
// grid (196, 2): block stages 48 output cols x full K=384 once
// (4 aligned chunks, proven stride-104 bank pattern), zero barriers in loop.
__global__ __launch_bounds__(256) void ffn2_p(
    const __hip_bfloat16* __restrict__ hbf, const __hip_bfloat16* __restrict__ W2T,
    const float* __restrict__ b2v, const __hip_bfloat16* __restrict__ x2,
    float* __restrict__ out) {
    __shared__ __hip_bfloat16 Bs[4][48][104];   // [K-chunk][col][k%96]
    int t = threadIdx.x, lane = t & 63, wave = t >> 6;
    int ch = blockIdx.y;                         // col-half: cols [ch*48, ch*48+48)
    int lr = lane & 15, kg = lane >> 4;
    const __hip_bfloat16* wslab = W2T + (size_t)ch * 48 * 384;
    for (int i = t * 8; i < 48 * 384; i += 256 * 8) {
        int r = i / 384, c = i % 384;
        *(short8*)&Bs[c / 96][r][c % 96] = *(const short8*)&wslab[(size_t)r * 384 + c];
    }
    __syncthreads();
    float bb[3];
#pragma unroll
    for (int ct = 0; ct < 3; ct++) bb[ct] = b2v[ch * 48 + ct * 16 + lr];

    for (int tile = blockIdx.x; tile < 391; tile += 196) {
        int row0 = tile * 128 + wave * 32;
        bool val0 = (row0 + 16 <= NN);
        bool val1 = (row0 + 32 <= NN);
        int ra0 = val0 ? row0 : 0;
        int ra1 = val1 ? (row0 + 16) : 0;
        const __hip_bfloat16* H0 = hbf + (size_t)(ra0 + lr) * FFND + kg * 8;
        const __hip_bfloat16* H1 = hbf + (size_t)(ra1 + lr) * FFND + kg * 8;
        f32x4 acc[2][3];
#pragma unroll
        for (int f = 0; f < 2; f++)
#pragma unroll
            for (int ct = 0; ct < 3; ct++) acc[f][ct] = (f32x4){0.f, 0.f, 0.f, 0.f};
#pragma unroll
        for (int kc = 0; kc < 12; kc++) {
            short8 a0 = *(const short8*)(H0 + kc * 32);
            short8 a1 = *(const short8*)(H1 + kc * 32);
#pragma unroll
            for (int ct = 0; ct < 3; ct++) {
                short8 bf_ = *(const short8*)&Bs[kc / 3][ct * 16 + lr][(kc % 3) * 32 + kg * 8];
                acc[0][ct] = __builtin_amdgcn_mfma_f32_16x16x32_bf16(a0, bf_, acc[0][ct], 0, 0, 0);
                acc[1][ct] = __builtin_amdgcn_mfma_f32_16x16x32_bf16(a1, bf_, acc[1][ct], 0, 0, 0);
            }
        }
#pragma unroll
        for (int f = 0; f < 2; f++) {
            if (f == 0 ? !val0 : !val1) continue;
            int crow = row0 + f * 16 + kg * 4;
#pragma unroll
            for (int ct = 0; ct < 3; ct++) {
                int col = ch * 48 + ct * 16 + lr;
#pragma unroll
                for (int r = 0; r < 4; r++) {
                    float o = acc[f][ct][r] + bb[ct]
                            + __bfloat162float(x2[(size_t)(crow + r) * 96 + col]);
                    out[(size_t)(crow + r) * 96 + col] = o;
                }
            }
        }
    }
}

// ---------------- Sparse attention gather (fp8 kv, software-pipelined) ----------------
__global__ __launch_bounds__(256) void attn_gather(
    const __hip_bfloat16* __restrict__ qbf, const unsigned char* __restrict__ kv,
    const uint2* __restrict__ rowrange, const unsigned short* __restrict__ srcs,
    __hip_bfloat16* __restrict__ abf) {
    int wave = (blockIdx.x * blockDim.x + threadIdx.x) >> 6;
    int lane = threadIdx.x & 63;
    if (wave >= NN) return;
    int dst = wave;
    int h = lane & 7;
    int eslot = lane >> 3;
    float qf[12];
    {
        const uint2* qp = (const uint2*)(qbf + (size_t)dst * HIDD + h * HD);
        uint2 u0 = qp[0], u1 = qp[1], u2 = qp[2];
        unsigned int w[6] = {u0.x, u0.y, u1.x, u1.y, u2.x, u2.y};
#pragma unroll
        for (int i = 0; i < 6; i++) {
            qf[2 * i]     = bf2f((unsigned short)(w[i] & 0xffffu));
            qf[2 * i + 1] = bf2f((unsigned short)(w[i] >> 16));
        }
    }
    uint2 rr = rowrange[dst];
    int beg = (int)rr.x, end = (int)rr.y;
    float acc[12];
#pragma unroll
    for (int i = 0; i < 12; i++) acc[i] = 0.0f;
    float zz = 0.0f;

    int e = beg + eslot;
    bool has = e < end;
    uint2 cA, cB, cC;
    if (has) {
        int src = (int)srcs[e];
        const uint2* kp = (const uint2*)(kv + (size_t)src * 192 + h * 24);
        cA = kp[0]; cB = kp[1]; cC = kp[2];
    }
    while (has) {
        int en = e + 8;
        bool hasn = en < end;
        uint2 nA, nB, nC;
        if (hasn) {
            int srcn = (int)srcs[en];
            const uint2* kp = (const uint2*)(kv + (size_t)srcn * 192 + h * 24);
            nA = kp[0]; nB = kp[1]; nC = kp[2];
        }
        f32x2 p;
        float dot = 0.0f;
        p = __builtin_amdgcn_cvt_pk_f32_fp8(cA.x, false); dot += p[0] * qf[0]  + p[1] * qf[1];
        p = __builtin_amdgcn_cvt_pk_f32_fp8(cA.x, true);  dot += p[0] * qf[2]  + p[1] * qf[3];
        p = __builtin_amdgcn_cvt_pk_f32_fp8(cA.y, false); dot += p[0] * qf[4]  + p[1] * qf[5];
        p = __builtin_amdgcn_cvt_pk_f32_fp8(cA.y, true);  dot += p[0] * qf[6]  + p[1] * qf[7];
        p = __builtin_amdgcn_cvt_pk_f32_fp8(cB.x, false); dot += p[0] * qf[8]  + p[1] * qf[9];
        p = __builtin_amdgcn_cvt_pk_f32_fp8(cB.x, true);  dot += p[0] * qf[10] + p[1] * qf[11];
        float s = fminf(fmaxf(dot * INV_SCALE, -5.0f), 5.0f);
        float sc = exp2f(s * LOG2E);
        p = __builtin_amdgcn_cvt_pk_f32_fp8(cB.y, false); acc[0]  += p[0] * sc; acc[1]  += p[1] * sc;
        p = __builtin_amdgcn_cvt_pk_f32_fp8(cB.y, true);  acc[2]  += p[0] * sc; acc[3]  += p[1] * sc;
        p = __builtin_amdgcn_cvt_pk_f32_fp8(cC.x, false); acc[4]  += p[0] * sc; acc[5]  += p[1] * sc;
        p = __builtin_amdgcn_cvt_pk_f32_fp8(cC.x, true);  acc[6]  += p[0] * sc; acc[7]  += p[1] * sc;
        p = __builtin_amdgcn_cvt_pk_f32_fp8(cC.y, false); acc[8]  += p[0] * sc; acc[9]  += p[1] * sc;
        p = __builtin_amdgcn_cvt_pk_f32_fp8(cC.y, true);  acc[10] += p[0] * sc; acc[11] += p[1] * sc;
        zz += sc;
        cA = nA; cB = nB; cC = nC;
        e = en; has = hasn;
    }
#pragma unroll
    for (int m = 8; m < 64; m <<= 1) {
#pragma unroll
        for (int i = 0; i < 12; i++) acc[i] += __shfl_xor(acc[i], m);
        zz += __shfl_xor(zz, m);
    }
    if (eslot == 0) {
        float inv = 1.0f / (zz + 1e-6f);
        __hip_bfloat16* ar = abf + (size_t)dst * HIDD + h * HD;
#pragma unroll
        for (int i = 0; i < 12; i++) ar[i] = __float2bfloat16(acc[i] * inv);
    }
}

extern "C" void kernel_launch(void* const* d_in, const int* in_sizes, int n_in,
                              void* d_out, int out_size, void* d_ws, size_t ws_size,
                              hipStream_t stream) {
    const float* x     = (const float*)d_in[0];
    const int*   ei    = (const int*)d_in[1];
    const float* ln1_g = (const float*)d_in[2];
    const float* ln1_b = (const float*)d_in[3];
    const float* Wq    = (const float*)d_in[4];
    const float* bq    = (const float*)d_in[5];
    const float* Wk    = (const float*)d_in[6];
    const float* bk    = (const float*)d_in[7];
    const float* Wv    = (const float*)d_in[8];
    const float* bv    = (const float*)d_in[9];
    const float* Wo    = (const float*)d_in[10];
    const float* bo    = (const float*)d_in[11];
    const float* ln2_g = (const float*)d_in[12];
    const float* ln2_b = (const float*)d_in[13];
    const float* W1    = (const float*)d_in[14];
    const float* b1    = (const float*)d_in[15];
    const float* W2    = (const float*)d_in[16];
    const float* b2    = (const float*)d_in[17];
    float* out = (float*)d_out;

    // Workspace layout (float units, NF = NN*96 = 4.8M floats):
    //   qbf  bf16 [0, 0.5NF)
    //   kv   fp8  [0.5NF, NF)       (NN*192 bytes)
    //   abf  bf16 [1.5NF, 2NF)
    //   hbf  bf16 [0, 2NF)          aliases qbf/kv/abf (dead by ffn1)
    //   x2   bf16 [2NF, 2.5NF)
    //   ybf  bf16 [2.5NF, 3NF)
    //   CSR at 3NF: rowrange[NN] uint2, srcs[NB*BSTRIDE] u16, gcursor[128],
    //               ebuf[NB*BSTRIDE] u32
    //   wbuf bf16 at 3.5NF (110592 bf16)
    float* ws = (float*)d_ws;
    const size_t NF = (size_t)NN * HIDD;
    __hip_bfloat16* qbf = (__hip_bfloat16*)ws;
    unsigned char*  kv  = (unsigned char*)(ws + NF / 2);
    __hip_bfloat16* abf = (__hip_bfloat16*)(ws + NF / 2 + NF);
    __hip_bfloat16* hbf = (__hip_bfloat16*)ws;
    __hip_bfloat16* x2  = (__hip_bfloat16*)(ws + 2 * NF);
    __hip_bfloat16* ybf = (__hip_bfloat16*)(ws + 2 * NF + NF / 2);
    int* ibase = (int*)(ws + 3 * NF);
    uint2* rowrange = (uint2*)ibase;                              // NN uint2
    unsigned short* srcs = (unsigned short*)(ibase + 2 * NN);     // NB*BSTRIDE u16
    int* gcursor = ibase + 2 * NN + (NB * BSTRIDE + 1) / 2;       // 128
    unsigned int* ebuf = (unsigned int*)(gcursor + 128);          // NB*BSTRIDE u32
    __hip_bfloat16* wbuf = (__hip_bfloat16*)(ws + 3 * NF + NF / 2);
    __hip_bfloat16* WoT = wbuf + 27648;
    __hip_bfloat16* W1T = wbuf + 36864;
    __hip_bfloat16* W2T = wbuf + 73728;

    const int MT = (NN + 127) / 128;             // 391

    // 1. P1: gcursor-init ∥ wconv ∥ LN1
    prep<<<433 + 12500, 256, 0, stream>>>(gcursor, Wq, Wk, Wv, Wo, W1, W2, wbuf,
                                          x, ln1_g, ln1_b, ybf);
    // 2. P2: bucket_scatter (fixed-stride) ∥ qkv MFMA
    scatter_qkv<<<391 + 3 * MT, 256, 0, stream>>>(ei, gcursor, ebuf,
                                                  ybf, wbuf, bq, bk, bv, qbf, kv);
    // 3. per-bucket CSR finalize
    bucket_build<<<NB, 1024, 0, stream>>>(ebuf, gcursor, rowrange, srcs);
    // 4. sparse attention
    attn_gather<<<(NN + 3) / 4, 256, 0, stream>>>(qbf, kv, rowrange, srcs, abf);
    // 5. output projection + residual + LN2 (x2 in bf16)
    proj_ln<<<MT, 256, 0, stream>>>(abf, WoT, bo, x, ln2_g, ln2_b, x2, ybf);
    // 6. FFN1 persistent-weight (+gelu)
    {
        dim3 g(98, 4);
        ffn1_p<<<g, 256, 0, stream>>>(ybf, W1T, b1, hbf);
    }
    // 7. FFN2 persistent-weight + residual
    {
        dim3 g(196, 2);
        ffn2_p<<<g, 256, 0, stream>>>(hbf, W2T, b2, x2, out);
    }
}

// Round 15
// 134.081 us; speedup vs baseline: 1.0670x; 1.0392x over previous
//
#include <hip/hip_runtime.h>
#include <hip/hip_bf16.h>
#include <math.h>

#define NN 50000
#define HIDD 96
#define NH 8
#define HD 12
#define FFND 384
#define NE 800000
#define NB 98            // buckets of 512 dst nodes
#define BSTRIDE 12288    // fixed edge capacity per bucket (mean 8192, +45 sigma)

#define INV_SCALE 0.28867513459481287f
#define LOG2E 1.4426950408889634f

typedef short short8 __attribute__((ext_vector_type(8)));
typedef float f32x4 __attribute__((ext_vector_type(4)));
typedef float f32x2 __attribute__((ext_vector_type(2)));

__device__ __forceinline__ float bf2f(unsigned short u) {
    union { unsigned int i; float f; } c;
    c.i = ((unsigned int)u) << 16;
    return c.f;
}

// ---------------- P1: gcursor-init ∥ wconv ∥ ln1 (one launch) ----------------
__global__ __launch_bounds__(256) void prep(
    int* __restrict__ gcursor,
    const float* __restrict__ Wq, const float* __restrict__ Wk,
    const float* __restrict__ Wv, const float* __restrict__ Wo,
    const float* __restrict__ W1, const float* __restrict__ W2,
    __hip_bfloat16* __restrict__ wbuf,
    const float* __restrict__ x, const float* __restrict__ g1,
    const float* __restrict__ b1, __hip_bfloat16* __restrict__ ybf) {
    int b = blockIdx.x;
    int t = threadIdx.x;
    if (b == 0) {
        if (t < 128) gcursor[t] = t * BSTRIDE;
        return;
    }
    if (b < 433) {
        int idx = b - 1;
        const float* W; __hip_bfloat16* D; int K, N; int i;
        if (idx < 144)      { W = W1; D = wbuf + 36864; K = 96;  N = 384; i = idx * 256 + t; }
        else if (idx < 288) { W = W2; D = wbuf + 73728; K = 384; N = 96;  i = (idx - 144) * 256 + t; }
        else {
            int slab = (idx - 288) / 36;
            W = (slab == 0) ? Wq : (slab == 1) ? Wk : (slab == 2) ? Wv : Wo;
            D = wbuf + slab * 9216; K = 96; N = 96;
            i = ((idx - 288) % 36) * 256 + t;
        }
        if (i < K * N) {
            int n = i / K, k = i % K;
            D[i] = __float2bfloat16(W[k * N + n]);
        }
    } else {
        int row = (b - 433) * 4 + (t >> 6);
        int lane = t & 63;
        if (row >= NN) return;
        const float* xr = x + (size_t)row * HIDD;
        float v0 = xr[lane];
        float v1 = (lane < 32) ? xr[64 + lane] : 0.0f;
        float s = v0 + v1, q = v0 * v0 + v1 * v1;
#pragma unroll
        for (int o = 32; o > 0; o >>= 1) {
            s += __shfl_xor(s, o);
            q += __shfl_xor(q, o);
        }
        float mean = s * (1.0f / 96.0f);
        float var = q * (1.0f / 96.0f) - mean * mean;
        float rs = rsqrtf(var + 1e-5f);
        __hip_bfloat16* yr = ybf + (size_t)row * HIDD;
        yr[lane] = __float2bfloat16((v0 - mean) * rs * g1[lane] + b1[lane]);
        if (lane < 32)
            yr[64 + lane] = __float2bfloat16((v1 - mean) * rs * g1[64 + lane] + b1[64 + lane]);
    }
}

// ---------------- P2: bucket_scatter ∥ merged qkv MFMA (one launch) ----------------
// blocks [0,391): edge scatter; [391,782): qkv — A-frags in regs, 3 weight slabs
// staged sequentially (ybf read ONCE).
__global__ __launch_bounds__(256) void scatter_qkv(
    const int* __restrict__ ei, int* __restrict__ gcursor,
    unsigned int* __restrict__ ebuf,
    const __hip_bfloat16* __restrict__ A, const __hip_bfloat16* __restrict__ wbuf,
    const float* __restrict__ bq, const float* __restrict__ bk,
    const float* __restrict__ bv,
    __hip_bfloat16* __restrict__ qbf, unsigned char* __restrict__ kv) {
    int b = blockIdx.x;
    int t = threadIdx.x;
    if (b < 391) {
        __shared__ int lcount[128];
        __shared__ int lbase[128];
        int e0 = b * 2048;
        if (t < 128) lcount[t] = 0;
        __syncthreads();
        int rank[8], dsts[8], srcv[8];
#pragma unroll
        for (int i = 0; i < 8; i++) {
            int e = e0 + t + i * 256;
            if (e < NE) {
                srcv[i] = ei[e];
                int d = ei[NE + e];
                dsts[i] = d;
                rank[i] = atomicAdd(&lcount[d >> 9], 1);
            } else dsts[i] = -1;
        }
        __syncthreads();
        if (t < 128) lbase[t] = lcount[t] ? atomicAdd(&gcursor[t], lcount[t]) : 0;
        __syncthreads();
#pragma unroll
        for (int i = 0; i < 8; i++) {
            if (dsts[i] >= 0) {
                int bk_ = dsts[i] >> 9;
                ebuf[lbase[bk_] + rank[i]] =
                    ((unsigned int)dsts[i] << 16) | (unsigned int)srcv[i];
            }
        }
    } else {
        __shared__ __hip_bfloat16 Bs[96][104];
        int xb = b - 391;
        int lane = t & 63, wave = t >> 6;
        int row0 = xb * 128 + wave * 32;
        int lr = lane & 15, kg = lane >> 4;
        bool val0 = (row0 + 16 <= NN);
        bool val1 = (row0 + 32 <= NN);
        int ra0 = val0 ? row0 : 0;
        int ra1 = val1 ? (row0 + 16) : 0;
        short8 a0[3], a1[3];
#pragma unroll
        for (int kc = 0; kc < 3; kc++) {
            a0[kc] = *(const short8*)&A[(size_t)(ra0 + lr) * 96 + kc * 32 + kg * 8];
            a1[kc] = *(const short8*)&A[(size_t)(ra1 + lr) * 96 + kc * 32 + kg * 8];
        }
        for (int y = 0; y < 3; y++) {
            const __hip_bfloat16* slab = wbuf + y * 9216;
            for (int i = t * 8; i < 96 * 96; i += 256 * 8) {
                int r = i / 96, c = i % 96;
                *(short8*)&Bs[r][c] = *(const short8*)&slab[r * 96 + c];
            }
            __syncthreads();
            f32x4 acc[2][6];
#pragma unroll
            for (int f = 0; f < 2; f++)
#pragma unroll
                for (int ct = 0; ct < 6; ct++) acc[f][ct] = (f32x4){0.f, 0.f, 0.f, 0.f};
#pragma unroll
            for (int kc = 0; kc < 3; kc++) {
#pragma unroll
                for (int ct = 0; ct < 6; ct++) {
                    short8 bf_ = *(const short8*)&Bs[ct * 16 + lr][kc * 32 + kg * 8];
                    acc[0][ct] = __builtin_amdgcn_mfma_f32_16x16x32_bf16(a0[kc], bf_, acc[0][ct], 0, 0, 0);
                    acc[1][ct] = __builtin_amdgcn_mfma_f32_16x16x32_bf16(a1[kc], bf_, acc[1][ct], 0, 0, 0);
                }
            }
            const float* bias = (y == 0) ? bq : (y == 1) ? bk : bv;
            int koff = (y == 2) ? 12 : 0;
#pragma unroll
            for (int f = 0; f < 2; f++) {
                if (f == 0 ? !val0 : !val1) continue;
                int crow = row0 + f * 16 + kg * 4;
#pragma unroll
                for (int ct = 0; ct < 6; ct++) {
                    int col = ct * 16 + lr;
                    float bb = bias[col];
#pragma unroll
                    for (int r = 0; r < 4; r++) {
                        float o = acc[f][ct][r] + bb;
                        if (y == 0) {
                            qbf[(size_t)(crow + r) * HIDD + col] = __float2bfloat16(o);
                        } else {
                            unsigned int enc =
                                (unsigned int)__builtin_amdgcn_cvt_pk_fp8_f32(o, o, 0, false);
                            kv[(size_t)(crow + r) * 192 + (col / 12) * 24 + koff + (col % 12)]
                                = (unsigned char)(enc & 0xffu);
                        }
                    }
                }
            }
            __syncthreads();
        }
    }
}

// ---------------- bucket build (1024 thr) ----------------
__global__ __launch_bounds__(1024) void bucket_build(
    const unsigned int* __restrict__ ebuf, const int* __restrict__ gcursor,
    uint2* __restrict__ rowrange, unsigned short* __restrict__ srcs) {
    __shared__ int cnt[512];
    int b = blockIdx.x;
    int t = threadIdx.x;
    int n0 = b * 512;
    int beg = b * BSTRIDE;
    int end = gcursor[b];
    if (t < 512) cnt[t] = 0;
    __syncthreads();
    for (int e = beg + t; e < end; e += 1024)
        atomicAdd(&cnt[(ebuf[e] >> 16) - n0], 1);
    __syncthreads();
    int my = (t < 512) ? cnt[t] : 0;
    for (int off = 1; off < 512; off <<= 1) {
        int v = (t >= off && t < 512) ? cnt[t - off] : 0;
        __syncthreads();
        if (t < 512) cnt[t] += v;
        __syncthreads();
    }
    int excl = (t > 0 && t < 512) ? cnt[t - 1] : 0;
    int base = beg + excl;
    if (t < 512 && n0 + t < NN)
        rowrange[n0 + t] = make_uint2((unsigned)base, (unsigned)(base + my));
    __syncthreads();
    if (t < 512) cnt[t] = base;
    __syncthreads();
    for (int e = beg + t; e < end; e += 1024) {
        unsigned int u = ebuf[e];
        int pos = atomicAdd(&cnt[(u >> 16) - n0], 1);
        srcs[pos] = (unsigned short)(u & 0xffffu);
    }
}

// ---------------- proj + LN2 fused (x2 out in bf16) ----------------
__global__ __launch_bounds__(256) void proj_ln(
    const __hip_bfloat16* __restrict__ A, const __hip_bfloat16* __restrict__ BT,
    const float* __restrict__ bias, const float* __restrict__ R,
    const float* __restrict__ g2, const float* __restrict__ b2v,
    __hip_bfloat16* __restrict__ x2, __hip_bfloat16* __restrict__ ybf) {
    constexpr int K = 96;
    __shared__ __hip_bfloat16 Bs[96][K + 8];
    int t = threadIdx.x;
    int lane = t & 63, wave = t >> 6;
    int row0 = blockIdx.x * 128 + wave * 32;
    int lr = lane & 15, kg = lane >> 4;
    bool val0 = (row0 + 16 <= NN);
    bool val1 = (row0 + 32 <= NN);
    int ra0 = val0 ? row0 : 0;
    int ra1 = val1 ? (row0 + 16) : 0;
    const __hip_bfloat16* A0 = A + (size_t)(ra0 + lr) * K + kg * 8;
    const __hip_bfloat16* A1 = A + (size_t)(ra1 + lr) * K + kg * 8;
    f32x4 acc[2][6];
#pragma unroll
    for (int f = 0; f < 2; f++)
#pragma unroll
        for (int ct = 0; ct < 6; ct++) acc[f][ct] = (f32x4){0.f, 0.f, 0.f, 0.f};

    for (int i = t * 8; i < 96 * K; i += 256 * 8) {
        int r = i / K, c = i % K;
        *(short8*)&Bs[r][c] = *(const short8*)&BT[(size_t)r * K + c];
    }
    __syncthreads();
#pragma unroll
    for (int kc = 0; kc < K; kc += 32) {
        short8 a0 = *(const short8*)(A0 + kc);
        short8 a1 = *(const short8*)(A1 + kc);
#pragma unroll
        for (int ct = 0; ct < 6; ct++) {
            short8 bf_ = *(const short8*)&Bs[ct * 16 + lr][kc + kg * 8];
            acc[0][ct] = __builtin_amdgcn_mfma_f32_16x16x32_bf16(a0, bf_, acc[0][ct], 0, 0, 0);
            acc[1][ct] = __builtin_amdgcn_mfma_f32_16x16x32_bf16(a1, bf_, acc[1][ct], 0, 0, 0);
        }
    }

    float bo_[6], gv[6], bv_[6];
#pragma unroll
    for (int ct = 0; ct < 6; ct++) {
        int col = ct * 16 + lr;
        bo_[ct] = bias[col];
        gv[ct]  = g2[col];
        bv_[ct] = b2v[col];
    }
#pragma unroll
    for (int f = 0; f < 2; f++) {
        if (f == 0 ? !val0 : !val1) continue;
        int crow = row0 + f * 16 + kg * 4;
#pragma unroll
        for (int r = 0; r < 4; r++) {
            int row = crow + r;
            float o[6], s1 = 0.f, s2 = 0.f;
#pragma unroll
            for (int ct = 0; ct < 6; ct++) {
                int col = ct * 16 + lr;
                float val = acc[f][ct][r] + bo_[ct] + R[(size_t)row * 96 + col];
                o[ct] = val; s1 += val; s2 += val * val;
            }
#pragma unroll
            for (int m = 1; m < 16; m <<= 1) {
                s1 += __shfl_xor(s1, m);
                s2 += __shfl_xor(s2, m);
            }
            float mu = s1 * (1.0f / 96.0f);
            float var = s2 * (1.0f / 96.0f) - mu * mu;
            float rs = rsqrtf(var + 1e-5f);
#pragma unroll
            for (int ct = 0; ct < 6; ct++) {
                int col = ct * 16 + lr;
                x2[(size_t)row * 96 + col] = __float2bfloat16(o[ct]);
                ybf[(size_t)row * 96 + col] =
                    __float2bfloat16((o[ct] - mu) * rs * gv[ct] + bv_[ct]);
            }
        }
    }
}

// ---------------- FFN1: A-frags in regs, 4 W1 slabs staged sequentially ----------------
// Block = 64 rows (4 waves x 16). ybf read ONCE per row.
__global__ __launch_bounds__(256) void ffn1_p(
    const __hip_bfloat16* __restrict__ ybf, const __hip_bfloat16* __restrict__ W1T,
    const float* __restrict__ b1, __hip_bfloat16* __restrict__ hbf) {
    __shared__ __hip_bfloat16 Bs[96][104];
    int t = threadIdx.x, lane = t & 63, wave = t >> 6;
    int lr = lane & 15, kg = lane >> 4;
    int row0 = blockIdx.x * 64 + wave * 16;
    bool valid = (row0 + 16 <= NN);
    int ra = valid ? row0 : 0;
    short8 af[3];
#pragma unroll
    for (int kc = 0; kc < 3; kc++)
        af[kc] = *(const short8*)&ybf[(size_t)(ra + lr) * 96 + kc * 32 + kg * 8];

    for (int s = 0; s < 4; s++) {
        const __hip_bfloat16* slab = W1T + (size_t)s * 96 * 96;
        for (int i = t * 8; i < 96 * 96; i += 256 * 8) {
            int r = i / 96, c = i % 96;
            *(short8*)&Bs[r][c] = *(const short8*)&slab[r * 96 + c];
        }
        __syncthreads();
        f32x4 acc[6];
#pragma unroll
        for (int ct = 0; ct < 6; ct++) acc[ct] = (f32x4){0.f, 0.f, 0.f, 0.f};
#pragma unroll
        for (int kc = 0; kc < 3; kc++) {
#pragma unroll
            for (int ct = 0; ct < 6; ct++) {
                short8 bf_ = *(const short8*)&Bs[ct * 16 + lr][kc * 32 + kg * 8];
                acc[ct] = __builtin_amdgcn_mfma_f32_16x16x32_bf16(af[kc], bf_, acc[ct], 0, 0, 0);
            }
        }
        if (valid) {
            int crow = row0 + kg * 4;
#pragma unroll
            for (int ct = 0; ct < 6; ct++) {
                int col = s * 96 + ct * 16 + lr;
                float bb = b1[col];
#pragma unroll
                for (int r = 0; r < 4; r++) {
                    float o = acc[ct][r] + bb;
                    o = 0.5f * o * (1.0f + erff(o * 0.70710678118654752f));
                    hbf[(size_t)(crow + r) * FFND + col] = __float2bfloat16(o);
                }
            }
        }
        __syncthreads();
    }
}

// ---------------- FFN2: H-frags in regs, 2 W2 col-halves staged sequentially ----------------
// Block = 64 rows. h read ONCE per row (was 2x).
__global__ __launch_bounds__(256) void ffn2_p(
    const __hip_bfloat16* __restrict__ hbf, const __hip_bfloat16* __restrict__ W2T,
    const float* __restrict__ b2v, const __hip_bfloat16* __restrict__ x2,
    float* __restrict__ out) {
    __shared__ __hip_bfloat16 Bs[4][48][104];   // 40KB, proven stride-104 pattern
    int t = threadIdx.x, lane = t & 63, wave = t >> 6;
    int lr = lane & 15, kg = lane >> 4;
    int row0 = blockIdx.x * 64 + wave * 16;
    bool valid = (row0 + 16 <= NN);
    int ra = valid ? row0 : 0;
    short8 hf[12];
#pragma unroll
    for (int kc = 0; kc < 12; kc++)
        hf[kc] = *(const short8*)&hbf[(size_t)(ra + lr) * FFND + kc * 32 + kg * 8];

    for (int ch = 0; ch < 2; ch++) {
        const __hip_bfloat16* wslab = W2T + (size_t)ch * 48 * 384;
        for (int i = t * 8; i < 48 * 384; i += 256 * 8) {
            int r = i / 384, c = i % 384;
            *(short8*)&Bs[c / 96][r][c % 96] = *(const short8*)&wslab[(size_t)r * 384 + c];
        }
        __syncthreads();
        f32x4 acc[3];
#pragma unroll
        for (int ct = 0; ct < 3; ct++) acc[ct] = (f32x4){0.f, 0.f, 0.f, 0.f};
#pragma unroll
        for (int kc = 0; kc < 12; kc++) {
#pragma unroll
            for (int ct = 0; ct < 3; ct++) {
                short8 bf_ = *(const short8*)&Bs[kc / 3][ct * 16 + lr][(kc % 3) * 32 + kg * 8];
                acc[ct] = __builtin_amdgcn_mfma_f32_16x16x32_bf16(hf[kc], bf_, acc[ct], 0, 0, 0);
            }
        }
        if (valid) {
            int crow = row0 + kg * 4;
#pragma unroll
            for (int ct = 0; ct < 3; ct++) {
                int col = ch * 48 + ct * 16 + lr;
                float bb = b2v[col];
#pragma unroll
                for (int r = 0; r < 4; r++) {
                    float o = acc[ct][r] + bb
                            + __bfloat162float(x2[(size_t)(crow + r) * 96 + col]);
                    out[(size_t)(crow + r) * 96 + col] = o;
                }
            }
        }
        __syncthreads();
    }
}

// ---------------- Sparse attention gather (fp8 kv, software-pipelined) ----------------
__global__ __launch_bounds__(256) void attn_gather(
    const __hip_bfloat16* __restrict__ qbf, const unsigned char* __restrict__ kv,
    const uint2* __restrict__ rowrange, const unsigned short* __restrict__ srcs,
    __hip_bfloat16* __restrict__ abf) {
    int wave = (blockIdx.x * blockDim.x + threadIdx.x) >> 6;
    int lane = threadIdx.x & 63;
    if (wave >= NN) return;
    int dst = wave;
    int h = lane & 7;
    int eslot = lane >> 3;
    float qf[12];
    {
        const uint2* qp = (const uint2*)(qbf + (size_t)dst * HIDD + h * HD);
        uint2 u0 = qp[0], u1 = qp[1], u2 = qp[2];
        unsigned int w[6] = {u0.x, u0.y, u1.x, u1.y, u2.x, u2.y};
#pragma unroll
        for (int i = 0; i < 6; i++) {
            qf[2 * i]     = bf2f((unsigned short)(w[i] & 0xffffu));
            qf[2 * i + 1] = bf2f((unsigned short)(w[i] >> 16));
        }
    }
    uint2 rr = rowrange[dst];
    int beg = (int)rr.x, end = (int)rr.y;
    float acc[12];
#pragma unroll
    for (int i = 0; i < 12; i++) acc[i] = 0.0f;
    float zz = 0.0f;

    int e = beg + eslot;
    bool has = e < end;
    uint2 cA, cB, cC;
    if (has) {
        int src = (int)srcs[e];
        const uint2* kp = (const uint2*)(kv + (size_t)src * 192 + h * 24);
        cA = kp[0]; cB = kp[1]; cC = kp[2];
    }
    while (has) {
        int en = e + 8;
        bool hasn = en < end;
        uint2 nA, nB, nC;
        if (hasn) {
            int srcn = (int)srcs[en];
            const uint2* kp = (const uint2*)(kv + (size_t)srcn * 192 + h * 24);
            nA = kp[0]; nB = kp[1]; nC = kp[2];
        }
        f32x2 p;
        float dot = 0.0f;
        p = __builtin_amdgcn_cvt_pk_f32_fp8(cA.x, false); dot += p[0] * qf[0]  + p[1] * qf[1];
        p = __builtin_amdgcn_cvt_pk_f32_fp8(cA.x, true);  dot += p[0] * qf[2]  + p[1] * qf[3];
        p = __builtin_amdgcn_cvt_pk_f32_fp8(cA.y, false); dot += p[0] * qf[4]  + p[1] * qf[5];
        p = __builtin_amdgcn_cvt_pk_f32_fp8(cA.y, true);  dot += p[0] * qf[6]  + p[1] * qf[7];
        p = __builtin_amdgcn_cvt_pk_f32_fp8(cB.x, false); dot += p[0] * qf[8]  + p[1] * qf[9];
        p = __builtin_amdgcn_cvt_pk_f32_fp8(cB.x, true);  dot += p[0] * qf[10] + p[1] * qf[11];
        float s = fminf(fmaxf(dot * INV_SCALE, -5.0f), 5.0f);
        float sc = exp2f(s * LOG2E);
        p = __builtin_amdgcn_cvt_pk_f32_fp8(cB.y, false); acc[0]  += p[0] * sc; acc[1]  += p[1] * sc;
        p = __builtin_amdgcn_cvt_pk_f32_fp8(cB.y, true);  acc[2]  += p[0] * sc; acc[3]  += p[1] * sc;
        p = __builtin_amdgcn_cvt_pk_f32_fp8(cC.x, false); acc[4]  += p[0] * sc; acc[5]  += p[1] * sc;
        p = __builtin_amdgcn_cvt_pk_f32_fp8(cC.x, true);  acc[6]  += p[0] * sc; acc[7]  += p[1] * sc;
        p = __builtin_amdgcn_cvt_pk_f32_fp8(cC.y, false); acc[8]  += p[0] * sc; acc[9]  += p[1] * sc;
        p = __builtin_amdgcn_cvt_pk_f32_fp8(cC.y, true);  acc[10] += p[0] * sc; acc[11] += p[1] * sc;
        zz += sc;
        cA = nA; cB = nB; cC = nC;
        e = en; has = hasn;
    }
#pragma unroll
    for (int m = 8; m < 64; m <<= 1) {
#pragma unroll
        for (int i = 0; i < 12; i++) acc[i] += __shfl_xor(acc[i], m);
        zz += __shfl_xor(zz, m);
    }
    if (eslot == 0) {
        float inv = 1.0f / (zz + 1e-6f);
        __hip_bfloat16* ar = abf + (size_t)dst * HIDD + h * HD;
#pragma unroll
        for (int i = 0; i < 12; i++) ar[i] = __float2bfloat16(acc[i] * inv);
    }
}

extern "C" void kernel_launch(void* const* d_in, const int* in_sizes, int n_in,
                              void* d_out, int out_size, void* d_ws, size_t ws_size,
                              hipStream_t stream) {
    const float* x     = (const float*)d_in[0];
    const int*   ei    = (const int*)d_in[1];
    const float* ln1_g = (const float*)d_in[2];
    const float* ln1_b = (const float*)d_in[3];
    const float* Wq    = (const float*)d_in[4];
    const float* bq    = (const float*)d_in[5];
    const float* Wk    = (const float*)d_in[6];
    const float* bk    = (const float*)d_in[7];
    const float* Wv    = (const float*)d_in[8];
    const float* bv    = (const float*)d_in[9];
    const float* Wo    = (const float*)d_in[10];
    const float* bo    = (const float*)d_in[11];
    const float* ln2_g = (const float*)d_in[12];
    const float* ln2_b = (const float*)d_in[13];
    const float* W1    = (const float*)d_in[14];
    const float* b1    = (const float*)d_in[15];
    const float* W2    = (const float*)d_in[16];
    const float* b2    = (const float*)d_in[17];
    float* out = (float*)d_out;

    // Workspace layout (float units, NF = NN*96 = 4.8M floats):
    //   qbf  bf16 [0, 0.5NF)
    //   kv   fp8  [0.5NF, NF)       (NN*192 bytes)
    //   abf  bf16 [1.5NF, 2NF)
    //   hbf  bf16 [0, 2NF)          aliases qbf/kv/abf (dead by ffn1)
    //   x2   bf16 [2NF, 2.5NF)
    //   ybf  bf16 [2.5NF, 3NF)
    //   CSR at 3NF: rowrange[NN] uint2, srcs[NB*BSTRIDE] u16, gcursor[128],
    //               ebuf[NB*BSTRIDE] u32
    //   wbuf bf16 at 3.5NF (110592 bf16)
    float* ws = (float*)d_ws;
    const size_t NF = (size_t)NN * HIDD;
    __hip_bfloat16* qbf = (__hip_bfloat16*)ws;
    unsigned char*  kv  = (unsigned char*)(ws + NF / 2);
    __hip_bfloat16* abf = (__hip_bfloat16*)(ws + NF / 2 + NF);
    __hip_bfloat16* hbf = (__hip_bfloat16*)ws;
    __hip_bfloat16* x2  = (__hip_bfloat16*)(ws + 2 * NF);
    __hip_bfloat16* ybf = (__hip_bfloat16*)(ws + 2 * NF + NF / 2);
    int* ibase = (int*)(ws + 3 * NF);
    uint2* rowrange = (uint2*)ibase;                              // NN uint2
    unsigned short* srcs = (unsigned short*)(ibase + 2 * NN);     // NB*BSTRIDE u16
    int* gcursor = ibase + 2 * NN + (NB * BSTRIDE + 1) / 2;       // 128
    unsigned int* ebuf = (unsigned int*)(gcursor + 128);          // NB*BSTRIDE u32
    __hip_bfloat16* wbuf = (__hip_bfloat16*)(ws + 3 * NF + NF / 2);
    __hip_bfloat16* WoT = wbuf + 27648;
    __hip_bfloat16* W1T = wbuf + 36864;
    __hip_bfloat16* W2T = wbuf + 73728;

    const int MT = (NN + 127) / 128;             // 391
    const int FT = (NN + 63) / 64;               // 782

    // 1. P1: gcursor-init ∥ wconv ∥ LN1
    prep<<<433 + 12500, 256, 0, stream>>>(gcursor, Wq, Wk, Wv, Wo, W1, W2, wbuf,
                                          x, ln1_g, ln1_b, ybf);
    // 2. P2: bucket_scatter ∥ merged qkv (ybf read once)
    scatter_qkv<<<391 + MT, 256, 0, stream>>>(ei, gcursor, ebuf,
                                              ybf, wbuf, bq, bk, bv, qbf, kv);
    // 3. per-bucket CSR finalize
    bucket_build<<<NB, 1024, 0, stream>>>(ebuf, gcursor, rowrange, srcs);
    // 4. sparse attention
    attn_gather<<<(NN + 3) / 4, 256, 0, stream>>>(qbf, kv, rowrange, srcs, abf);
    // 5. output projection + residual + LN2 (x2 in bf16)
    proj_ln<<<MT, 256, 0, stream>>>(abf, WoT, bo, x, ln2_g, ln2_b, x2, ybf);
    // 6. FFN1 (ybf read once, 4 slabs staged)
    ffn1_p<<<FT, 256, 0, stream>>>(ybf, W1T, b1, hbf);
    // 7. FFN2 (h read once, 2 col-halves staged)
    ffn2_p<<<FT, 256, 0, stream>>>(hbf, W2T, b2, x2, out);
}

// Round 16
// 126.513 us; speedup vs baseline: 1.1308x; 1.0598x over previous
//
#include <hip/hip_runtime.h>
#include <hip/hip_bf16.h>
#include <math.h>

#define NN 50000
#define HIDD 96
#define NH 8
#define HD 12
#define FFND 384
#define NE 800000
#define NB 98            // buckets of 512 dst nodes
#define BSTRIDE 12288    // fixed edge capacity per bucket (mean 8192, +45 sigma)

#define INV_SCALE 0.28867513459481287f
#define LOG2E 1.4426950408889634f

typedef short short8 __attribute__((ext_vector_type(8)));
typedef float f32x4 __attribute__((ext_vector_type(4)));
typedef float f32x2 __attribute__((ext_vector_type(2)));

__device__ __forceinline__ float bf2f(unsigned short u) {
    union { unsigned int i; float f; } c;
    c.i = ((unsigned int)u) << 16;
    return c.f;
}

// exact fp8->bf16 (fp8 e4m3 values are exactly representable in bf16)
__device__ __forceinline__ short f2bf_exact(float f) {
    return (short)(__float_as_uint(f) >> 16);
}

__device__ __forceinline__ short8 fp8x8_to_bf16x8(uint2 u) {
    f32x2 p0 = __builtin_amdgcn_cvt_pk_f32_fp8(u.x, false);
    f32x2 p1 = __builtin_amdgcn_cvt_pk_f32_fp8(u.x, true);
    f32x2 p2 = __builtin_amdgcn_cvt_pk_f32_fp8(u.y, false);
    f32x2 p3 = __builtin_amdgcn_cvt_pk_f32_fp8(u.y, true);
    short8 r;
    r[0] = f2bf_exact(p0[0]); r[1] = f2bf_exact(p0[1]);
    r[2] = f2bf_exact(p1[0]); r[3] = f2bf_exact(p1[1]);
    r[4] = f2bf_exact(p2[0]); r[5] = f2bf_exact(p2[1]);
    r[6] = f2bf_exact(p3[0]); r[7] = f2bf_exact(p3[1]);
    return r;
}

// ---------------- P1: bucket_scatter ∥ wconv ∥ ln1 (one launch) ----------------
// gcursor holds bucket-RELATIVE offsets (memset to 0 before launch).
// blocks [0,391): scatter; [391,823): wconv; [823,13323): LN1.
__global__ __launch_bounds__(256) void prep2(
    const int* __restrict__ ei, int* __restrict__ gcursor,
    unsigned int* __restrict__ ebuf,
    const float* __restrict__ Wq, const float* __restrict__ Wk,
    const float* __restrict__ Wv, const float* __restrict__ Wo,
    const float* __restrict__ W1, const float* __restrict__ W2,
    __hip_bfloat16* __restrict__ wbuf,
    const float* __restrict__ x, const float* __restrict__ g1,
    const float* __restrict__ b1, __hip_bfloat16* __restrict__ ybf) {
    int b = blockIdx.x;
    int t = threadIdx.x;
    if (b < 391) {
        // --- edge scatter to fixed-stride buckets ---
        __shared__ int lcount[128];
        __shared__ int lbase[128];
        int e0 = b * 2048;
        if (t < 128) lcount[t] = 0;
        __syncthreads();
        int rank[8], dsts[8], srcv[8];
#pragma unroll
        for (int i = 0; i < 8; i++) {
            int e = e0 + t + i * 256;
            if (e < NE) {
                srcv[i] = ei[e];
                int d = ei[NE + e];
                dsts[i] = d;
                rank[i] = atomicAdd(&lcount[d >> 9], 1);
            } else dsts[i] = -1;
        }
        __syncthreads();
        if (t < 128) lbase[t] = lcount[t] ? atomicAdd(&gcursor[t], lcount[t]) : 0;
        __syncthreads();
#pragma unroll
        for (int i = 0; i < 8; i++) {
            if (dsts[i] >= 0) {
                int bk_ = dsts[i] >> 9;
                ebuf[bk_ * BSTRIDE + lbase[bk_] + rank[i]] =
                    ((unsigned int)dsts[i] << 16) | (unsigned int)srcv[i];
            }
        }
    } else if (b < 823) {
        // --- wconv: WT[n][k] = bf16(W[k][n]) ---
        int idx = b - 391;
        const float* W; __hip_bfloat16* D; int K, N; int i;
        if (idx < 144)      { W = W1; D = wbuf + 36864; K = 96;  N = 384; i = idx * 256 + t; }
        else if (idx < 288) { W = W2; D = wbuf + 73728; K = 384; N = 96;  i = (idx - 144) * 256 + t; }
        else {
            int slab = (idx - 288) / 36;
            W = (slab == 0) ? Wq : (slab == 1) ? Wk : (slab == 2) ? Wv : Wo;
            D = wbuf + slab * 9216; K = 96; N = 96;
            i = ((idx - 288) % 36) * 256 + t;
        }
        if (i < K * N) {
            int n = i / K, k = i % K;
            D[i] = __float2bfloat16(W[k * N + n]);
        }
    } else {
        // --- LN1: one wave per row ---
        int row = (b - 823) * 4 + (t >> 6);
        int lane = t & 63;
        if (row >= NN) return;
        const float* xr = x + (size_t)row * HIDD;
        float v0 = xr[lane];
        float v1 = (lane < 32) ? xr[64 + lane] : 0.0f;
        float s = v0 + v1, q = v0 * v0 + v1 * v1;
#pragma unroll
        for (int o = 32; o > 0; o >>= 1) {
            s += __shfl_xor(s, o);
            q += __shfl_xor(q, o);
        }
        float mean = s * (1.0f / 96.0f);
        float var = q * (1.0f / 96.0f) - mean * mean;
        float rs = rsqrtf(var + 1e-5f);
        __hip_bfloat16* yr = ybf + (size_t)row * HIDD;
        yr[lane] = __float2bfloat16((v0 - mean) * rs * g1[lane] + b1[lane]);
        if (lane < 32)
            yr[64 + lane] = __float2bfloat16((v1 - mean) * rs * g1[64 + lane] + b1[64 + lane]);
    }
}

// ---------------- P2: bucket_build ∥ qkv MFMA (one launch, 512 thr) ----------------
// blocks [0,98): per-bucket CSR finalize; [98,489): qkv (8 waves x 16 rows).
__global__ __launch_bounds__(512) void build_qkv(
    const unsigned int* __restrict__ ebuf, const int* __restrict__ gcursor,
    uint2* __restrict__ rowrange, unsigned short* __restrict__ srcs,
    const __hip_bfloat16* __restrict__ A, const __hip_bfloat16* __restrict__ wbuf,
    const float* __restrict__ bq, const float* __restrict__ bk,
    const float* __restrict__ bv,
    __hip_bfloat16* __restrict__ qbf, unsigned char* __restrict__ kv) {
    __shared__ int cnt[512];
    __shared__ __hip_bfloat16 Bs[96][104];
    int b = blockIdx.x;
    int t = threadIdx.x;
    if (b < NB) {
        // --- bucket build ---
        int n0 = b * 512;
        int beg = b * BSTRIDE;
        int end = beg + gcursor[b];
        cnt[t] = 0;
        __syncthreads();
        for (int e = beg + t; e < end; e += 512)
            atomicAdd(&cnt[(ebuf[e] >> 16) - n0], 1);
        __syncthreads();
        int my = cnt[t];
        for (int off = 1; off < 512; off <<= 1) {
            int v = (t >= off) ? cnt[t - off] : 0;
            __syncthreads();
            cnt[t] += v;
            __syncthreads();
        }
        int excl = (t > 0) ? cnt[t - 1] : 0;
        int base = beg + excl;
        if (n0 + t < NN)
            rowrange[n0 + t] = make_uint2((unsigned)base, (unsigned)(base + my));
        __syncthreads();
        cnt[t] = base;
        __syncthreads();
        for (int e = beg + t; e < end; e += 512) {
            unsigned int u = ebuf[e];
            int pos = atomicAdd(&cnt[(u >> 16) - n0], 1);
            srcs[pos] = (unsigned short)(u & 0xffffu);
        }
    } else {
        // --- qkv: 8 waves x 16 rows, A-frags in regs, 3 slabs staged ---
        int xb = b - NB;
        int lane = t & 63, wave = t >> 6;
        int row0 = xb * 128 + wave * 16;
        int lr = lane & 15, kg = lane >> 4;
        bool valid = (row0 + 16 <= NN);
        int ra = valid ? row0 : 0;
        short8 af[3];
#pragma unroll
        for (int kc = 0; kc < 3; kc++)
            af[kc] = *(const short8*)&A[(size_t)(ra + lr) * 96 + kc * 32 + kg * 8];
        for (int y = 0; y < 3; y++) {
            const __hip_bfloat16* slab = wbuf + y * 9216;
            for (int i = t * 8; i < 96 * 96; i += 512 * 8) {
                int r = i / 96, c = i % 96;
                *(short8*)&Bs[r][c] = *(const short8*)&slab[r * 96 + c];
            }
            __syncthreads();
            f32x4 acc[6];
#pragma unroll
            for (int ct = 0; ct < 6; ct++) acc[ct] = (f32x4){0.f, 0.f, 0.f, 0.f};
#pragma unroll
            for (int kc = 0; kc < 3; kc++) {
#pragma unroll
                for (int ct = 0; ct < 6; ct++) {
                    short8 bf_ = *(const short8*)&Bs[ct * 16 + lr][kc * 32 + kg * 8];
                    acc[ct] = __builtin_amdgcn_mfma_f32_16x16x32_bf16(af[kc], bf_, acc[ct], 0, 0, 0);
                }
            }
            if (valid) {
                const float* bias = (y == 0) ? bq : (y == 1) ? bk : bv;
                int koff = (y == 2) ? 12 : 0;
                int crow = row0 + kg * 4;
#pragma unroll
                for (int ct = 0; ct < 6; ct++) {
                    int col = ct * 16 + lr;
                    float bb = bias[col];
#pragma unroll
                    for (int r = 0; r < 4; r++) {
                        float o = acc[ct][r] + bb;
                        if (y == 0) {
                            qbf[(size_t)(crow + r) * HIDD + col] = __float2bfloat16(o);
                        } else {
                            unsigned int enc =
                                (unsigned int)__builtin_amdgcn_cvt_pk_fp8_f32(o, o, 0, false);
                            kv[(size_t)(crow + r) * 192 + (col / 12) * 24 + koff + (col % 12)]
                                = (unsigned char)(enc & 0xffu);
                        }
                    }
                }
            }
            __syncthreads();
        }
    }
}

// ---------------- proj + LN2 fused (x2 out in bf16) ----------------
__global__ __launch_bounds__(256) void proj_ln(
    const __hip_bfloat16* __restrict__ A, const __hip_bfloat16* __restrict__ BT,
    const float* __restrict__ bias, const float* __restrict__ R,
    const float* __restrict__ g2, const float* __restrict__ b2v,
    __hip_bfloat16* __restrict__ x2, __hip_bfloat16* __restrict__ ybf) {
    constexpr int K = 96;
    __shared__ __hip_bfloat16 Bs[96][K + 8];
    int t = threadIdx.x;
    int lane = t & 63, wave = t >> 6;
    int row0 = blockIdx.x * 128 + wave * 32;
    int lr = lane & 15, kg = lane >> 4;
    bool val0 = (row0 + 16 <= NN);
    bool val1 = (row0 + 32 <= NN);
    int ra0 = val0 ? row0 : 0;
    int ra1 = val1 ? (row0 + 16) : 0;
    const __hip_bfloat16* A0 = A + (size_t)(ra0 + lr) * K + kg * 8;
    const __hip_bfloat16* A1 = A + (size_t)(ra1 + lr) * K + kg * 8;
    f32x4 acc[2][6];
#pragma unroll
    for (int f = 0; f < 2; f++)
#pragma unroll
        for (int ct = 0; ct < 6; ct++) acc[f][ct] = (f32x4){0.f, 0.f, 0.f, 0.f};

    for (int i = t * 8; i < 96 * K; i += 256 * 8) {
        int r = i / K, c = i % K;
        *(short8*)&Bs[r][c] = *(const short8*)&BT[(size_t)r * K + c];
    }
    __syncthreads();
#pragma unroll
    for (int kc = 0; kc < K; kc += 32) {
        short8 a0 = *(const short8*)(A0 + kc);
        short8 a1 = *(const short8*)(A1 + kc);
#pragma unroll
        for (int ct = 0; ct < 6; ct++) {
            short8 bf_ = *(const short8*)&Bs[ct * 16 + lr][kc + kg * 8];
            acc[0][ct] = __builtin_amdgcn_mfma_f32_16x16x32_bf16(a0, bf_, acc[0][ct], 0, 0, 0);
            acc[1][ct] = __builtin_amdgcn_mfma_f32_16x16x32_bf16(a1, bf_, acc[1][ct], 0, 0, 0);
        }
    }

    float bo_[6], gv[6], bv_[6];
#pragma unroll
    for (int ct = 0; ct < 6; ct++) {
        int col = ct * 16 + lr;
        bo_[ct] = bias[col];
        gv[ct]  = g2[col];
        bv_[ct] = b2v[col];
    }
#pragma unroll
    for (int f = 0; f < 2; f++) {
        if (f == 0 ? !val0 : !val1) continue;
        int crow = row0 + f * 16 + kg * 4;
#pragma unroll
        for (int r = 0; r < 4; r++) {
            int row = crow + r;
            float o[6], s1 = 0.f, s2 = 0.f;
#pragma unroll
            for (int ct = 0; ct < 6; ct++) {
                int col = ct * 16 + lr;
                float val = acc[f][ct][r] + bo_[ct] + R[(size_t)row * 96 + col];
                o[ct] = val; s1 += val; s2 += val * val;
            }
#pragma unroll
            for (int m = 1; m < 16; m <<= 1) {
                s1 += __shfl_xor(s1, m);
                s2 += __shfl_xor(s2, m);
            }
            float mu = s1 * (1.0f / 96.0f);
            float var = s2 * (1.0f / 96.0f) - mu * mu;
            float rs = rsqrtf(var + 1e-5f);
#pragma unroll
            for (int ct = 0; ct < 6; ct++) {
                int col = ct * 16 + lr;
                x2[(size_t)row * 96 + col] = __float2bfloat16(o[ct]);
                ybf[(size_t)row * 96 + col] =
                    __float2bfloat16((o[ct] - mu) * rs * gv[ct] + bv_[ct]);
            }
        }
    }
}

// ---------------- FFN1: A-frags in regs, 4 W1 slabs staged; h out in fp8 ----------------
__global__ __launch_bounds__(256) void ffn1_p(
    const __hip_bfloat16* __restrict__ ybf, const __hip_bfloat16* __restrict__ W1T,
    const float* __restrict__ b1, unsigned char* __restrict__ hbf8) {
    __shared__ __hip_bfloat16 Bs[96][104];
    int t = threadIdx.x, lane = t & 63, wave = t >> 6;
    int lr = lane & 15, kg = lane >> 4;
    int row0 = blockIdx.x * 64 + wave * 16;
    bool valid = (row0 + 16 <= NN);
    int ra = valid ? row0 : 0;
    short8 af[3];
#pragma unroll
    for (int kc = 0; kc < 3; kc++)
        af[kc] = *(const short8*)&ybf[(size_t)(ra + lr) * 96 + kc * 32 + kg * 8];

    for (int s = 0; s < 4; s++) {
        const __hip_bfloat16* slab = W1T + (size_t)s * 96 * 96;
        for (int i = t * 8; i < 96 * 96; i += 256 * 8) {
            int r = i / 96, c = i % 96;
            *(short8*)&Bs[r][c] = *(const short8*)&slab[r * 96 + c];
        }
        __syncthreads();
        f32x4 acc[6];
#pragma unroll
        for (int ct = 0; ct < 6; ct++) acc[ct] = (f32x4){0.f, 0.f, 0.f, 0.f};
#pragma unroll
        for (int kc = 0; kc < 3; kc++) {
#pragma unroll
            for (int ct = 0; ct < 6; ct++) {
                short8 bf_ = *(const short8*)&Bs[ct * 16 + lr][kc * 32 + kg * 8];
                acc[ct] = __builtin_amdgcn_mfma_f32_16x16x32_bf16(af[kc], bf_, acc[ct], 0, 0, 0);
            }
        }
        if (valid) {
            int crow = row0 + kg * 4;
#pragma unroll
            for (int ct = 0; ct < 6; ct++) {
                int col = s * 96 + ct * 16 + lr;
                float bb = b1[col];
#pragma unroll
                for (int r = 0; r < 4; r++) {
                    float o = acc[ct][r] + bb;
                    o = 0.5f * o * (1.0f + erff(o * 0.70710678118654752f));
                    unsigned int enc =
                        (unsigned int)__builtin_amdgcn_cvt_pk_fp8_f32(o, o, 0, false);
                    hbf8[(size_t)(crow + r) * FFND + col] = (unsigned char)(enc & 0xffu);
                }
            }
        }
        __syncthreads();
    }
}

// ---------------- FFN2: fp8 H-frags decoded to regs, 2 W2 col-halves staged ----------------
__global__ __launch_bounds__(256) void ffn2_p(
    const unsigned char* __restrict__ hbf8, const __hip_bfloat16* __restrict__ W2T,
    const float* __restrict__ b2v, const __hip_bfloat16* __restrict__ x2,
    float* __restrict__ out) {
    __shared__ __hip_bfloat16 Bs[4][48][104];
    int t = threadIdx.x, lane = t & 63, wave = t >> 6;
    int lr = lane & 15, kg = lane >> 4;
    int row0 = blockIdx.x * 64 + wave * 16;
    bool valid = (row0 + 16 <= NN);
    int ra = valid ? row0 : 0;
    const unsigned char* H = hbf8 + (size_t)(ra + lr) * FFND + kg * 8;
    short8 hf[12];
#pragma unroll
    for (int kc = 0; kc < 12; kc++)
        hf[kc] = fp8x8_to_bf16x8(*(const uint2*)(H + kc * 32));

    for (int ch = 0; ch < 2; ch++) {
        const __hip_bfloat16* wslab = W2T + (size_t)ch * 48 * 384;
        for (int i = t * 8; i < 48 * 384; i += 256 * 8) {
            int r = i / 384, c = i % 384;
            *(short8*)&Bs[c / 96][r][c % 96] = *(const short8*)&wslab[(size_t)r * 384 + c];
        }
        __syncthreads();
        f32x4 acc[3];
#pragma unroll
        for (int ct = 0; ct < 3; ct++) acc[ct] = (f32x4){0.f, 0.f, 0.f, 0.f};
#pragma unroll
        for (int kc = 0; kc < 12; kc++) {
#pragma unroll
            for (int ct = 0; ct < 3; ct++) {
                short8 bf_ = *(const short8*)&Bs[kc / 3][ct * 16 + lr][(kc % 3) * 32 + kg * 8];
                acc[ct] = __builtin_amdgcn_mfma_f32_16x16x32_bf16(hf[kc], bf_, acc[ct], 0, 0, 0);
            }
        }
        if (valid) {
            int crow = row0 + kg * 4;
#pragma unroll
            for (int ct = 0; ct < 3; ct++) {
                int col = ch * 48 + ct * 16 + lr;
                float bb = b2v[col];
#pragma unroll
                for (int r = 0; r < 4; r++) {
                    float o = acc[ct][r] + bb
                            + __bfloat162float(x2[(size_t)(crow + r) * 96 + col]);
                    out[(size_t)(crow + r) * 96 + col] = o;
                }
            }
        }
        __syncthreads();
    }
}

// ---------------- Sparse attention gather (fp8 kv, software-pipelined) ----------------
__global__ __launch_bounds__(256) void attn_gather(
    const __hip_bfloat16* __restrict__ qbf, const unsigned char* __restrict__ kv,
    const uint2* __restrict__ rowrange, const unsigned short* __restrict__ srcs,
    __hip_bfloat16* __restrict__ abf) {
    int wave = (blockIdx.x * blockDim.x + threadIdx.x) >> 6;
    int lane = threadIdx.x & 63;
    if (wave >= NN) return;
    int dst = wave;
    int h = lane & 7;
    int eslot = lane >> 3;
    float qf[12];
    {
        const uint2* qp = (const uint2*)(qbf + (size_t)dst * HIDD + h * HD);
        uint2 u0 = qp[0], u1 = qp[1], u2 = qp[2];
        unsigned int w[6] = {u0.x, u0.y, u1.x, u1.y, u2.x, u2.y};
#pragma unroll
        for (int i = 0; i < 6; i++) {
            qf[2 * i]     = bf2f((unsigned short)(w[i] & 0xffffu));
            qf[2 * i + 1] = bf2f((unsigned short)(w[i] >> 16));
        }
    }
    uint2 rr = rowrange[dst];
    int beg = (int)rr.x, end = (int)rr.y;
    float acc[12];
#pragma unroll
    for (int i = 0; i < 12; i++) acc[i] = 0.0f;
    float zz = 0.0f;

    int e = beg + eslot;
    bool has = e < end;
    uint2 cA, cB, cC;
    if (has) {
        int src = (int)srcs[e];
        const uint2* kp = (const uint2*)(kv + (size_t)src * 192 + h * 24);
        cA = kp[0]; cB = kp[1]; cC = kp[2];
    }
    while (has) {
        int en = e + 8;
        bool hasn = en < end;
        uint2 nA, nB, nC;
        if (hasn) {
            int srcn = (int)srcs[en];
            const uint2* kp = (const uint2*)(kv + (size_t)srcn * 192 + h * 24);
            nA = kp[0]; nB = kp[1]; nC = kp[2];
        }
        f32x2 p;
        float dot = 0.0f;
        p = __builtin_amdgcn_cvt_pk_f32_fp8(cA.x, false); dot += p[0] * qf[0]  + p[1] * qf[1];
        p = __builtin_amdgcn_cvt_pk_f32_fp8(cA.x, true);  dot += p[0] * qf[2]  + p[1] * qf[3];
        p = __builtin_amdgcn_cvt_pk_f32_fp8(cA.y, false); dot += p[0] * qf[4]  + p[1] * qf[5];
        p = __builtin_amdgcn_cvt_pk_f32_fp8(cA.y, true);  dot += p[0] * qf[6]  + p[1] * qf[7];
        p = __builtin_amdgcn_cvt_pk_f32_fp8(cB.x, false); dot += p[0] * qf[8]  + p[1] * qf[9];
        p = __builtin_amdgcn_cvt_pk_f32_fp8(cB.x, true);  dot += p[0] * qf[10] + p[1] * qf[11];
        float s = fminf(fmaxf(dot * INV_SCALE, -5.0f), 5.0f);
        float sc = exp2f(s * LOG2E);
        p = __builtin_amdgcn_cvt_pk_f32_fp8(cB.y, false); acc[0]  += p[0] * sc; acc[1]  += p[1] * sc;
        p = __builtin_amdgcn_cvt_pk_f32_fp8(cB.y, true);  acc[2]  += p[0] * sc; acc[3]  += p[1] * sc;
        p = __builtin_amdgcn_cvt_pk_f32_fp8(cC.x, false); acc[4]  += p[0] * sc; acc[5]  += p[1] * sc;
        p = __builtin_amdgcn_cvt_pk_f32_fp8(cC.x, true);  acc[6]  += p[0] * sc; acc[7]  += p[1] * sc;
        p = __builtin_amdgcn_cvt_pk_f32_fp8(cC.y, false); acc[8]  += p[0] * sc; acc[9]  += p[1] * sc;
        p = __builtin_amdgcn_cvt_pk_f32_fp8(cC.y, true);  acc[10] += p[0] * sc; acc[11] += p[1] * sc;
        zz += sc;
        cA = nA; cB = nB; cC = nC;
        e = en; has = hasn;
    }
#pragma unroll
    for (int m = 8; m < 64; m <<= 1) {
#pragma unroll
        for (int i = 0; i < 12; i++) acc[i] += __shfl_xor(acc[i], m);
        zz += __shfl_xor(zz, m);
    }
    if (eslot == 0) {
        float inv = 1.0f / (zz + 1e-6f);
        __hip_bfloat16* ar = abf + (size_t)dst * HIDD + h * HD;
#pragma unroll
        for (int i = 0; i < 12; i++) ar[i] = __float2bfloat16(acc[i] * inv);
    }
}

extern "C" void kernel_launch(void* const* d_in, const int* in_sizes, int n_in,
                              void* d_out, int out_size, void* d_ws, size_t ws_size,
                              hipStream_t stream) {
    const float* x     = (const float*)d_in[0];
    const int*   ei    = (const int*)d_in[1];
    const float* ln1_g = (const float*)d_in[2];
    const float* ln1_b = (const float*)d_in[3];
    const float* Wq    = (const float*)d_in[4];
    const float* bq    = (const float*)d_in[5];
    const float* Wk    = (const float*)d_in[6];
    const float* bk    = (const float*)d_in[7];
    const float* Wv    = (const float*)d_in[8];
    const float* bv    = (const float*)d_in[9];
    const float* Wo    = (const float*)d_in[10];
    const float* bo    = (const float*)d_in[11];
    const float* ln2_g = (const float*)d_in[12];
    const float* ln2_b = (const float*)d_in[13];
    const float* W1    = (const float*)d_in[14];
    const float* b1    = (const float*)d_in[15];
    const float* W2    = (const float*)d_in[16];
    const float* b2    = (const float*)d_in[17];
    float* out = (float*)d_out;

    // Workspace layout (float units, NF = NN*96 = 4.8M floats):
    //   qbf  bf16 [0, 0.5NF)
    //   kv   fp8  [0.5NF, NF)       (NN*192 bytes)
    //   abf  bf16 [1.5NF, 2NF)
    //   hbf8 fp8  [0, NF)            aliases qbf/kv (dead by ffn1)
    //   x2   bf16 [2NF, 2.5NF)
    //   ybf  bf16 [2.5NF, 3NF)
    //   CSR at 3NF: rowrange[NN] uint2, srcs[NB*BSTRIDE] u16, gcursor[128],
    //               ebuf[NB*BSTRIDE] u32
    //   wbuf bf16 at 3.5NF (110592 bf16)
    float* ws = (float*)d_ws;
    const size_t NF = (size_t)NN * HIDD;
    __hip_bfloat16* qbf = (__hip_bfloat16*)ws;
    unsigned char*  kv  = (unsigned char*)(ws + NF / 2);
    __hip_bfloat16* abf = (__hip_bfloat16*)(ws + NF / 2 + NF);
    unsigned char*  hbf8 = (unsigned char*)ws;
    __hip_bfloat16* x2  = (__hip_bfloat16*)(ws + 2 * NF);
    __hip_bfloat16* ybf = (__hip_bfloat16*)(ws + 2 * NF + NF / 2);
    int* ibase = (int*)(ws + 3 * NF);
    uint2* rowrange = (uint2*)ibase;                              // NN uint2
    unsigned short* srcs = (unsigned short*)(ibase + 2 * NN);     // NB*BSTRIDE u16
    int* gcursor = ibase + 2 * NN + (NB * BSTRIDE + 1) / 2;       // 128
    unsigned int* ebuf = (unsigned int*)(gcursor + 128);          // NB*BSTRIDE u32
    __hip_bfloat16* wbuf = (__hip_bfloat16*)(ws + 3 * NF + NF / 2);
    __hip_bfloat16* WoT = wbuf + 27648;
    __hip_bfloat16* W1T = wbuf + 36864;
    __hip_bfloat16* W2T = wbuf + 73728;

    const int MT = (NN + 127) / 128;             // 391
    const int FT = (NN + 63) / 64;               // 782

    // 0. zero relative bucket cursors (DMA node)
    hipMemsetAsync(gcursor, 0, 128 * sizeof(int), stream);
    // 1. P1: scatter ∥ wconv ∥ LN1
    prep2<<<823 + 12500, 256, 0, stream>>>(ei, gcursor, ebuf,
                                           Wq, Wk, Wv, Wo, W1, W2, wbuf,
                                           x, ln1_g, ln1_b, ybf);
    // 2. P2: bucket_build ∥ qkv
    build_qkv<<<NB + MT, 512, 0, stream>>>(ebuf, gcursor, rowrange, srcs,
                                           ybf, wbuf, bq, bk, bv, qbf, kv);
    // 3. sparse attention
    attn_gather<<<(NN + 3) / 4, 256, 0, stream>>>(qbf, kv, rowrange, srcs, abf);
    // 4. output projection + residual + LN2 (x2 in bf16)
    proj_ln<<<MT, 256, 0, stream>>>(abf, WoT, bo, x, ln2_g, ln2_b, x2, ybf);
    // 5. FFN1 (fp8 h out)
    ffn1_p<<<FT, 256, 0, stream>>>(ybf, W1T, b1, hbf8);
    // 6. FFN2 (fp8 h in)
    ffn2_p<<<FT, 256, 0, stream>>>(hbf8, W2T, b2, x2, out);
}